// Round 13
// baseline (232.821 us; speedup 1.0000x reference)
//
#include <hip/hip_runtime.h>

#define CC 96
#define C3 288
#define HH 256
#define WW 256
#define HWC 65536
#define NHEADS 8
#define W2 32

typedef __bf16 bf16x8 __attribute__((ext_vector_type(8)));
typedef float f32x4 __attribute__((ext_vector_type(4)));
typedef unsigned short us8v __attribute__((ext_vector_type(8)));

typedef const __attribute__((address_space(1))) void* gas1_t;
typedef __attribute__((address_space(3))) void* las3_t;

#define BAR_LG() asm volatile("s_waitcnt lgkmcnt(0)\ns_barrier" ::: "memory")

__device__ __forceinline__ float bf2f(unsigned short u) {
  return __uint_as_float(((unsigned)u) << 16);
}
__device__ __forceinline__ unsigned short f2bf(float f) {
  unsigned u = __float_as_uint(f);
  unsigned r = u + 0x7fffu + ((u >> 16) & 1u);
  return (unsigned short)(r >> 16);
}
__device__ __forceinline__ unsigned cvt_pk_bf16(float lo, float hi) {
  unsigned r;
  asm("v_cvt_pk_bf16_f32 %0, %1, %2" : "=v"(r) : "v"(lo), "v"(hi));
  return r;
}

// K1 v7: qkv conv1x1 via bf16 MFMA. Double-buffered global_load_lds DMA with
// COUNTED vmcnt (never 0 in main loop): per-wave/iter VMEM = 6 DMA + 3 stores,
// so tile i is safe at vmcnt(12) steady-state (6/9 in prologue, 6 at tail).
// grid (128, 3, bc), block 256 (4 waves). LDS 74.75KB -> 2 blocks/CU.
__global__ __launch_bounds__(256, 2) void k1_qkv_mfma(
    const float* __restrict__ x, const float* __restrict__ qw,
    const float* __restrict__ qb, unsigned short* __restrict__ pre, int b0)
{
  __shared__ __align__(16) char smem[76544];
  // X: [2][96 ic][64 px] fp32 @0/@24576 ; As [64][106] us @49152 ; tD [96][72] us @62720
  unsigned short* As = (unsigned short*)(smem + 49152);
  unsigned short* tD = (unsigned short*)(smem + 62720);
  const int t = threadIdx.x;
  const int o0 = blockIdx.y * 96;
  const int bz = blockIdx.z;
  const float* xb = x + (size_t)(b0 + bz) * CC * HWC;

  const int w = t >> 6, lane = t & 63;
  const int wm = w & 1, wn = w >> 1;
  const int row = lane & 15, kg = lane >> 4;

  // weights + bias into registers
  bf16x8 bfr[3][3];
  float bias[3];
#pragma unroll
  for (int nt = 0; nt < 3; ++nt) {
    int ocl = wn * 48 + nt * 16 + row;
    bias[nt] = qb[o0 + ocl];
#pragma unroll
    for (int kk = 0; kk < 3; ++kk) {
      const float* wp = qw + (size_t)(o0 + ocl) * 96 + kk * 32 + kg * 8;
      float4 w0 = *reinterpret_cast<const float4*>(wp);
      float4 w1 = *reinterpret_cast<const float4*>(wp + 4);
      us8v u;
      u[0] = f2bf(w0.x); u[1] = f2bf(w0.y); u[2] = f2bf(w0.z); u[3] = f2bf(w0.w);
      u[4] = f2bf(w1.x); u[5] = f2bf(w1.y); u[6] = f2bf(w1.z); u[7] = f2bf(w1.w);
      bfr[kk][nt] = *reinterpret_cast<bf16x8*>(&u);
    }
  }

  int sic[3], sp4[3];
#pragma unroll
  for (int r = 0; r < 3; ++r) {
    int lin = r * 256 + t;
    sic[r] = lin >> 4;          // ic-pair 0..47
    sp4[r] = (lin & 15) * 4;    // px 0..60
  }

  int p0 = blockIdx.x * 512;
  // prologue: DMA(0)->X0, DMA(1)->X1  (12 outstanding per wave)
#pragma unroll
  for (int ii = 0; ii < 2; ++ii) {
    const float* xsrc = xb + p0 + ii * 64;
    char* xdst = smem + ii * 24576;
#pragma unroll
    for (int j = 0; j < 6; ++j) {
      int r0 = j * 16 + w * 4;
      const float* ga = xsrc + (size_t)(r0 + (lane >> 4)) * HWC + (lane & 15) * 4;
      __builtin_amdgcn_global_load_lds((gas1_t)(const void*)ga,
                                       (las3_t)(void*)(xdst + r0 * 256), 16, 0, 0);
    }
  }
  __builtin_amdgcn_sched_barrier(0);

#pragma unroll
  for (int i = 0; i < 8; ++i) {
    // A: wait exactly tile i's DMA (counted; never drains newer DMAs)
    if (i == 0 || i == 7)
      asm volatile("s_waitcnt vmcnt(6) lgkmcnt(0)\ns_barrier" ::: "memory");
    else if (i == 1)
      asm volatile("s_waitcnt vmcnt(9) lgkmcnt(0)\ns_barrier" ::: "memory");
    else
      asm volatile("s_waitcnt vmcnt(12) lgkmcnt(0)\ns_barrier" ::: "memory");

    // B: cvt X[i&1] [ic][px] -> As [px][ic] (packed-pair u32)
    const float4* x4 = (const float4*)(smem + (i & 1) * 24576);
#pragma unroll
    for (int r = 0; r < 3; ++r) {
      float4 v0 = x4[(2 * sic[r]) * 16 + (sp4[r] >> 2)];
      float4 v1 = x4[(2 * sic[r] + 1) * 16 + (sp4[r] >> 2)];
      unsigned pk_[4];
      pk_[0] = cvt_pk_bf16(v0.x, v1.x);
      pk_[1] = cvt_pk_bf16(v0.y, v1.y);
      pk_[2] = cvt_pk_bf16(v0.z, v1.z);
      pk_[3] = cvt_pk_bf16(v0.w, v1.w);
#pragma unroll
      for (int j = 0; j < 4; ++j)
        *reinterpret_cast<unsigned*>(&As[(sp4[r] + j) * 106 + 2 * sic[r]]) = pk_[j];
    }
    // C: As ready; all X[i&1] reads complete
    BAR_LG();

    // D: issue DMA(i+2) into X[i&1] (in flight across ~1.5 iterations)
    if (i < 6) {
      const float* xsrc = xb + p0 + 128;
      char* xdst = smem + (i & 1) * 24576;
#pragma unroll
      for (int j = 0; j < 6; ++j) {
        int r0 = j * 16 + w * 4;
        const float* ga = xsrc + (size_t)(r0 + (lane >> 4)) * HWC + (lane & 15) * 4;
        __builtin_amdgcn_global_load_lds((gas1_t)(const void*)ga,
                                         (las3_t)(void*)(xdst + r0 * 256), 16, 0, 0);
      }
      __builtin_amdgcn_sched_barrier(0);
    }

    // E: MFMA
    f32x4 acc[2][3];
#pragma unroll
    for (int mt = 0; mt < 2; ++mt)
#pragma unroll
      for (int nt = 0; nt < 3; ++nt) acc[mt][nt] = (f32x4){0.f, 0.f, 0.f, 0.f};
#pragma unroll
    for (int kk = 0; kk < 3; ++kk) {
      bf16x8 a[2];
#pragma unroll
      for (int mt = 0; mt < 2; ++mt)
        a[mt] = *reinterpret_cast<const bf16x8*>(
            &As[(wm * 32 + mt * 16 + row) * 106 + kk * 32 + kg * 8]);
#pragma unroll
      for (int mt = 0; mt < 2; ++mt)
#pragma unroll
        for (int nt = 0; nt < 3; ++nt)
          acc[mt][nt] = __builtin_amdgcn_mfma_f32_16x16x32_bf16(
              a[mt], bfr[kk][nt], acc[mt][nt], 0, 0, 0);
    }

    // F: epilogue bias + bf16 -> tD
#pragma unroll
    for (int nt = 0; nt < 3; ++nt) {
      int ocl = wn * 48 + nt * 16 + row;
      float bv = bias[nt];
#pragma unroll
      for (int mt = 0; mt < 2; ++mt) {
        int pxl = wm * 32 + mt * 16 + kg * 4;
        f32x4 v = acc[mt][nt];
        unsigned pk0 = cvt_pk_bf16(v[0] + bv, v[1] + bv);
        unsigned pk1 = cvt_pk_bf16(v[2] + bv, v[3] + bv);
        *reinterpret_cast<unsigned*>(&tD[ocl * 72 + pxl]) = pk0;
        *reinterpret_cast<unsigned*>(&tD[ocl * 72 + pxl + 2]) = pk1;
      }
    }
    // G: tD ready
    BAR_LG();

    // H: coalesced readback + global stores (3 VMEM stores/wave)
    unsigned short* preb = pre + ((size_t)bz * C3 + o0) * HWC + p0;
#pragma unroll
    for (int r = 0; r < 3; ++r) {
      int lin = r * 256 + t;
      int oc = lin >> 3, ch = lin & 7;
      us8v v = *reinterpret_cast<const us8v*>(&tD[oc * 72 + ch * 8]);
      *reinterpret_cast<us8v*>(preb + (size_t)oc * HWC + ch * 8) = v;
    }
    p0 += 64;
  }
}

// K2: depthwise 3x3 + bias, LDS-free register-rolling. grid (288, 8, bc).
__global__ __launch_bounds__(256) void k2_dw(
    const unsigned short* __restrict__ pre, const float* __restrict__ dww,
    const float* __restrict__ dwb, unsigned short* __restrict__ dwo)
{
  const int t = threadIdx.x;
  const int c3 = blockIdx.x;
  const int hb = blockIdx.y;
  const int bz = blockIdx.z;
  const size_t choff = ((size_t)bz * C3 + c3) * HWC;
  const int team = t >> 5, tl = t & 31;
  const int h0 = hb * 32 + team * 4;

  us8v rin[6];
#pragma unroll
  for (int r = 0; r < 6; ++r) {
    int hh = h0 - 1 + r;
    if (hh >= 0 && hh < HH)
      rin[r] = *reinterpret_cast<const us8v*>(pre + choff + (size_t)hh * WW + tl * 8);
    else
      rin[r] = (us8v){0, 0, 0, 0, 0, 0, 0, 0};
  }

  float wg[9];
#pragma unroll
  for (int i = 0; i < 9; ++i) wg[i] = dww[c3 * 9 + i];
  const float bias = dwb[c3];

  float f[6][8];
  float lf[6], rt[6];
#pragma unroll
  for (int r = 0; r < 6; ++r) {
#pragma unroll
    for (int j = 0; j < 8; ++j) f[r][j] = bf2f(rin[r][j]);
    float l = __shfl_up(f[r][7], 1, 32);
    float rr = __shfl_down(f[r][0], 1, 32);
    lf[r] = (tl == 0) ? 0.f : l;
    rt[r] = (tl == 31) ? 0.f : rr;
  }

#pragma unroll
  for (int orow = 0; orow < 4; ++orow) {
    float o[8];
#pragma unroll
    for (int j = 0; j < 8; ++j) o[j] = bias;
#pragma unroll
    for (int k = 0; k < 3; ++k) {
      const int r = orow + k;
      const float w0 = wg[k * 3 + 0], w1 = wg[k * 3 + 1], w2 = wg[k * 3 + 2];
      o[0] = fmaf(lf[r], w0, fmaf(f[r][0], w1, fmaf(f[r][1], w2, o[0])));
#pragma unroll
      for (int j = 1; j < 7; ++j)
        o[j] = fmaf(f[r][j - 1], w0, fmaf(f[r][j], w1, fmaf(f[r][j + 1], w2, o[j])));
      o[7] = fmaf(f[r][6], w0, fmaf(f[r][7], w1, fmaf(rt[r], w2, o[7])));
    }
    us8v u;
#pragma unroll
    for (int j = 0; j < 8; ++j) u[j] = f2bf(o[j]);
    *reinterpret_cast<us8v*>((unsigned short*)dwo + choff + (size_t)(h0 + orow) * WW + tl * 8) = u;
  }
}

// K3 v3: Gram via bf16 MFMA. grid (24, 8, bc), block 256 (4 waves).
__global__ __launch_bounds__(256, 4) void k3_gram(
    const unsigned short* __restrict__ dwo, float* __restrict__ g,
    float* __restrict__ ssq)
{
  __shared__ __align__(16) unsigned short qT[32 * 264];
  __shared__ __align__(16) unsigned short kT[32 * 264];
  const int t = threadIdx.x;
  const int cg0 = blockIdx.x;
  const int head = blockIdx.y, bz = blockIdx.z;
  const int lane = t & 63, wave = t >> 6;
  const int mt = wave & 1, nt = wave >> 1;
  const int l15 = lane & 15, l4 = lane >> 4;
  const int cg = t & 7;
  int rp[4];
#pragma unroll
  for (int r = 0; r < 4; ++r) rp[r] = (r * 256 + t) >> 3;

  const unsigned short* qbase = dwo + ((size_t)bz * C3 + cg0 * 4) * HWC + head * W2;
  const unsigned short* kbase = qbase + (size_t)CC * HWC;

  ushort4 qa[4], qb_[4], ka[4], kb_[4];
#pragma unroll
  for (int r = 0; r < 4; ++r) {
    qa[r] = *reinterpret_cast<const ushort4*>(qbase + (size_t)(2 * rp[r]) * WW + cg * 4);
    qb_[r] = *reinterpret_cast<const ushort4*>(qbase + (size_t)(2 * rp[r] + 1) * WW + cg * 4);
    ka[r] = *reinterpret_cast<const ushort4*>(kbase + (size_t)(2 * rp[r]) * WW + cg * 4);
    kb_[r] = *reinterpret_cast<const ushort4*>(kbase + (size_t)(2 * rp[r] + 1) * WW + cg * 4);
  }

  f32x4 acc = (f32x4){0.f, 0.f, 0.f, 0.f};
  float ssum_q = 0.f, ssum_k = 0.f;

  for (int cc = 0; cc < 4; ++cc) {
#pragma unroll
    for (int r = 0; r < 4; ++r) {
      unsigned short aq0[4] = {qa[r].x, qa[r].y, qa[r].z, qa[r].w};
      unsigned short aq1[4] = {qb_[r].x, qb_[r].y, qb_[r].z, qb_[r].w};
      unsigned short ak0[4] = {ka[r].x, ka[r].y, ka[r].z, ka[r].w};
      unsigned short ak1[4] = {kb_[r].x, kb_[r].y, kb_[r].z, kb_[r].w};
#pragma unroll
      for (int j = 0; j < 4; ++j) {
        int dwi = (cg * 4 + j) * 132 + rp[r];
        *(reinterpret_cast<unsigned*>(qT) + dwi) =
            (unsigned)aq0[j] | ((unsigned)aq1[j] << 16);
        *(reinterpret_cast<unsigned*>(kT) + dwi) =
            (unsigned)ak0[j] | ((unsigned)ak1[j] << 16);
      }
    }
    if (cc < 3) {
      const unsigned short* qn = qbase + (size_t)(cc + 1) * HWC;
      const unsigned short* kn = kbase + (size_t)(cc + 1) * HWC;
#pragma unroll
      for (int r = 0; r < 4; ++r) {
        qa[r] = *reinterpret_cast<const ushort4*>(qn + (size_t)(2 * rp[r]) * WW + cg * 4);
        qb_[r] = *reinterpret_cast<const ushort4*>(qn + (size_t)(2 * rp[r] + 1) * WW + cg * 4);
        ka[r] = *reinterpret_cast<const ushort4*>(kn + (size_t)(2 * rp[r]) * WW + cg * 4);
        kb_[r] = *reinterpret_cast<const ushort4*>(kn + (size_t)(2 * rp[r] + 1) * WW + cg * 4);
      }
    }
    __builtin_amdgcn_sched_barrier(0);
    __syncthreads();
#pragma unroll
    for (int kk = 0; kk < 8; ++kk) {
      bf16x8 a = *reinterpret_cast<const bf16x8*>(
          &qT[(mt * 16 + l15) * 264 + kk * 32 + l4 * 8]);
      bf16x8 b = *reinterpret_cast<const bf16x8*>(
          &kT[(nt * 16 + l15) * 264 + kk * 32 + l4 * 8]);
      acc = __builtin_amdgcn_mfma_f32_16x16x32_bf16(a, b, acc, 0, 0, 0);
    }
    {
      const int i = t & 31, seg = t >> 5;
#pragma unroll
      for (int m = 0; m < 4; ++m) {
        us8v vq = *reinterpret_cast<const us8v*>(&qT[i * 264 + seg * 32 + m * 8]);
        us8v vk = *reinterpret_cast<const us8v*>(&kT[i * 264 + seg * 32 + m * 8]);
#pragma unroll
        for (int e = 0; e < 8; ++e) {
          float fq = bf2f(vq[e]), fk = bf2f(vk[e]);
          ssum_q = fmaf(fq, fq, ssum_q);
          ssum_k = fmaf(fk, fk, ssum_k);
        }
      }
    }
    __syncthreads();
  }

  float* gb = g + ((size_t)bz * NHEADS + head) * 1024;
#pragma unroll
  for (int reg = 0; reg < 4; ++reg)
    atomicAdd(&gb[(nt * 16 + l15) * 32 + mt * 16 + l4 * 4 + reg], acc[reg]);

  float* red = reinterpret_cast<float*>(qT);
  red[t] = ssum_q;
  red[256 + t] = ssum_k;
  __syncthreads();
  if (t < 32) {
    float sq = 0.f, sk = 0.f;
#pragma unroll
    for (int p = 0; p < 8; ++p) { sq += red[t + 32 * p]; sk += red[256 + t + 32 * p]; }
    atomicAdd(&ssq[(size_t)bz * 512 + head * W2 + t], sq);
    atomicAdd(&ssq[(size_t)bz * 512 + 256 + head * W2 + t], sk);
  }
}

// K4b: normalize + temperature + softmax. grid (8, bc), block 64.
__global__ __launch_bounds__(64) void k4b_softmax(
    const float* __restrict__ g, const float* __restrict__ ssq,
    const float* __restrict__ temp, float* __restrict__ attn)
{
  const int t = threadIdx.x;
  const int head = blockIdx.x, bz = blockIdx.y;
  if (t >= 32) return;
  const int i = t;
  const float* gb = g + ((size_t)bz * NHEADS + head) * 1024;
  const float* sq_ = ssq + (size_t)bz * 512 + head * W2;
  const float* sk_ = ssq + (size_t)bz * 512 + 256 + head * W2;
  float invq = 1.f / fmaxf(sqrtf(sq_[i]), 1e-12f);
  float tpq = temp[head] * invq;
  float row[32];
  float m = -1e30f;
#pragma unroll
  for (int j = 0; j < 32; ++j) {
    float invk = 1.f / fmaxf(sqrtf(sk_[j]), 1e-12f);
    float v = gb[j * 32 + i] * tpq * invk;
    row[j] = v;
    m = fmaxf(m, v);
  }
  float ssum = 0;
#pragma unroll
  for (int j = 0; j < 32; ++j) { row[j] = expf(row[j] - m); ssum += row[j]; }
  float inv = 1.f / ssum;
  float* ap = attn + ((size_t)bz * NHEADS + head) * 1024 + i * 32;
#pragma unroll
  for (int j = 0; j < 32; ++j) ap[j] = row[j] * inv;
}

// K5a: t = attn @ v via MFMA. grid (384, bc), block 256 (4 waves).
__global__ __launch_bounds__(256) void k5a_attnv(
    const unsigned short* __restrict__ dwo, const float* __restrict__ attn,
    unsigned short* __restrict__ tbuf)
{
  __shared__ __align__(16) unsigned short vsm[64 * 264];
  __shared__ __align__(16) unsigned short atn_s[256 * 36];
  const int t = threadIdx.x;
  const int tile = blockIdx.x;
  const int bz = blockIdx.y;
  const size_t R0 = (size_t)tile * 64;
  const unsigned short* vsrc = dwo + ((size_t)bz * C3 + 2 * CC) * HWC + R0 * 256;

  us8v vv[8];
#pragma unroll
  for (int j = 0; j < 8; ++j)
    vv[j] = *reinterpret_cast<const us8v*>(vsrc + (size_t)(j * 256 + t) * 8);
  float4 av[8];
  {
    const float* ap = attn + (size_t)bz * 8192 + t * 32;
#pragma unroll
    for (int k = 0; k < 8; ++k)
      av[k] = *reinterpret_cast<const float4*>(ap + k * 4);
  }
  __builtin_amdgcn_sched_barrier(0);
#pragma unroll
  for (int j = 0; j < 8; ++j) {
    int n = j * 256 + t;
    int row = n >> 5, c8 = n & 31;
    *reinterpret_cast<us8v*>(&vsm[row * 264 + c8 * 8]) = vv[j];
  }
#pragma unroll
  for (int k = 0; k < 8; ++k) {
    ushort4 u;
    u.x = f2bf(av[k].x); u.y = f2bf(av[k].y); u.z = f2bf(av[k].z); u.w = f2bf(av[k].w);
    *reinterpret_cast<ushort4*>(&atn_s[t * 36 + k * 4]) = u;
  }
  __syncthreads();

  const int wave = t >> 6, lane = t & 63;
  const int mrow = lane & 15, kg = lane >> 4;

  bf16x8 a[8], b[16];
#pragma unroll
  for (int hd = 0; hd < 8; ++hd)
    a[hd] = *reinterpret_cast<const bf16x8*>(
        &vsm[(wave * 16 + mrow) * 264 + hd * 32 + kg * 8]);
#pragma unroll
  for (int hd = 0; hd < 8; ++hd)
#pragma unroll
    for (int it = 0; it < 2; ++it)
      b[hd * 2 + it] = *reinterpret_cast<const bf16x8*>(
          &atn_s[(hd * 32 + it * 16 + mrow) * 36 + kg * 8]);

  f32x4 acc[16];
#pragma unroll
  for (int q = 0; q < 16; ++q) acc[q] = (f32x4){0.f, 0.f, 0.f, 0.f};
#pragma unroll
  for (int hd = 0; hd < 8; ++hd)
#pragma unroll
    for (int it = 0; it < 2; ++it)
      acc[hd * 2 + it] = __builtin_amdgcn_mfma_f32_16x16x32_bf16(
          a[hd], b[hd * 2 + it], acc[hd * 2 + it], 0, 0, 0);
  __syncthreads();

#pragma unroll
  for (int hd = 0; hd < 8; ++hd)
#pragma unroll
    for (int it = 0; it < 2; ++it) {
      f32x4 v = acc[hd * 2 + it];
      int col = hd * 32 + it * 16 + mrow;
#pragma unroll
      for (int r = 0; r < 4; ++r)
        vsm[(wave * 16 + kg * 4 + r) * 264 + col] = f2bf(v[r]);
    }
  unsigned short* tdst = tbuf + (size_t)bz * CC * HWC + R0 * 256;
#pragma unroll
  for (int k = 0; k < 8; ++k) {
    int n = k * 64 + lane;
    int rloc = n >> 5, c8 = n & 31;
    us8v v = *reinterpret_cast<const us8v*>(&vsm[(wave * 16 + rloc) * 264 + c8 * 8]);
    *reinterpret_cast<us8v*>(tdst + ((size_t)(wave * 16 + rloc)) * 256 + c8 * 8) = v;
  }
}

// K5b v2b (known-good): out = proj(t) + pb via MFMA. 64-px tiles x 8.
__global__ __launch_bounds__(256, 4) void k5b_proj(
    const unsigned short* __restrict__ tbuf, const float* __restrict__ pw,
    const float* __restrict__ pb, float* __restrict__ out, int b0)
{
  __shared__ __align__(16) unsigned short As2[2][64 * 106];
  const int t = threadIdx.x;
  const int bz = blockIdx.y;
  const unsigned short* tb = tbuf + (size_t)bz * CC * HWC;

  const int wave = t >> 6, lane = t & 63;
  const int wm = wave & 1, wn = wave >> 1;
  const int row = lane & 15, kg = lane >> 4;

  bf16x8 bfr[3][3];
  float bias[3];
#pragma unroll
  for (int nt = 0; nt < 3; ++nt) {
    int ocl = wn * 48 + nt * 16 + row;
    bias[nt] = pb[ocl];
#pragma unroll
    for (int kk = 0; kk < 3; ++kk) {
      const float* wp = pw + (size_t)ocl * 96 + kk * 32 + kg * 8;
      float4 w0 = *reinterpret_cast<const float4*>(wp);
      float4 w1 = *reinterpret_cast<const float4*>(wp + 4);
      us8v u;
      u[0] = f2bf(w0.x); u[1] = f2bf(w0.y); u[2] = f2bf(w0.z); u[3] = f2bf(w0.w);
      u[4] = f2bf(w1.x); u[5] = f2bf(w1.y); u[6] = f2bf(w1.z); u[7] = f2bf(w1.w);
      bfr[kk][nt] = *reinterpret_cast<bf16x8*>(&u);
    }
  }

  int sic[3], sp4[3];
#pragma unroll
  for (int r = 0; r < 3; ++r) {
    int lin = r * 256 + t;
    sic[r] = lin >> 4;
    sp4[r] = (lin & 15) * 4;
  }

  int p0 = blockIdx.x * 512;
  ushort4 ua0[3], ua1[3];
#pragma unroll
  for (int r = 0; r < 3; ++r) {
    ua0[r] = *reinterpret_cast<const ushort4*>(tb + (size_t)(2 * sic[r]) * HWC + p0 + sp4[r]);
    ua1[r] = *reinterpret_cast<const ushort4*>(tb + (size_t)(2 * sic[r] + 1) * HWC + p0 + sp4[r]);
  }

  for (int i = 0; i < 8; ++i) {
    unsigned short* Ac = As2[i & 1];
#pragma unroll
    for (int r = 0; r < 3; ++r) {
      unsigned short a0[4] = {ua0[r].x, ua0[r].y, ua0[r].z, ua0[r].w};
      unsigned short a1[4] = {ua1[r].x, ua1[r].y, ua1[r].z, ua1[r].w};
#pragma unroll
      for (int j = 0; j < 4; ++j) {
        unsigned pk = (unsigned)a0[j] | ((unsigned)a1[j] << 16);
        *reinterpret_cast<unsigned*>(&Ac[(sp4[r] + j) * 106 + 2 * sic[r]]) = pk;
      }
    }
    if (i < 7) {
      int p0n = p0 + 64;
#pragma unroll
      for (int r = 0; r < 3; ++r) {
        ua0[r] = *reinterpret_cast<const ushort4*>(tb + (size_t)(2 * sic[r]) * HWC + p0n + sp4[r]);
        ua1[r] = *reinterpret_cast<const ushort4*>(tb + (size_t)(2 * sic[r] + 1) * HWC + p0n + sp4[r]);
      }
    }
    __syncthreads();

    f32x4 acc[2][3];
#pragma unroll
    for (int mt = 0; mt < 2; ++mt)
#pragma unroll
      for (int nt = 0; nt < 3; ++nt) acc[mt][nt] = (f32x4){0.f, 0.f, 0.f, 0.f};
#pragma unroll
    for (int kk = 0; kk < 3; ++kk) {
      bf16x8 a[2];
#pragma unroll
      for (int mt = 0; mt < 2; ++mt)
        a[mt] = *reinterpret_cast<const bf16x8*>(
            &Ac[(wm * 32 + mt * 16 + row) * 106 + kk * 32 + kg * 8]);
#pragma unroll
      for (int mt = 0; mt < 2; ++mt)
#pragma unroll
        for (int nt = 0; nt < 3; ++nt)
          acc[mt][nt] = __builtin_amdgcn_mfma_f32_16x16x32_bf16(
              a[mt], bfr[kk][nt], acc[mt][nt], 0, 0, 0);
    }
    __syncthreads();

    float* tD = (float*)As2;   // [96][68] fp32, spans both buffers
#pragma unroll
    for (int nt = 0; nt < 3; ++nt) {
      int ocl = wn * 48 + nt * 16 + row;
      float bv = bias[nt];
#pragma unroll
      for (int mt = 0; mt < 2; ++mt) {
        int pxl = wm * 32 + mt * 16 + kg * 4;
        f32x4 v = acc[mt][nt];
        float4 w = make_float4(v[0] + bv, v[1] + bv, v[2] + bv, v[3] + bv);
        *reinterpret_cast<float4*>(&tD[ocl * 68 + pxl]) = w;
      }
    }
    __syncthreads();
    float* ob = out + (size_t)(b0 + bz) * CC * HWC + p0;
#pragma unroll
    for (int r = 0; r < 6; ++r) {
      int lin = r * 256 + t;
      int o = lin >> 4, p4 = (lin & 15) * 4;
      float4 v = *reinterpret_cast<const float4*>(&tD[o * 68 + p4]);
      *reinterpret_cast<float4*>(ob + (size_t)o * HWC + p4) = v;
    }
    __syncthreads();
    p0 += 64;
  }
}

extern "C" void kernel_launch(void* const* d_in, const int* in_sizes, int n_in,
                              void* d_out, int out_size, void* d_ws, size_t ws_size,
                              hipStream_t stream)
{
  const float* x      = (const float*)d_in[0];
  const float* qkv_w  = (const float*)d_in[1];
  const float* qkv_b  = (const float*)d_in[2];
  const float* dw_w   = (const float*)d_in[3];
  const float* dw_b   = (const float*)d_in[4];
  const float* proj_w = (const float*)d_in[5];
  const float* proj_b = (const float*)d_in[6];
  const float* temp   = (const float*)d_in[7];
  float* out = (float*)d_out;

  const size_t per_pre  = (size_t)C3 * HWC * 2;
  const size_t per_ssq  = (size_t)2 * 256 * 4;
  const size_t per_attn = (size_t)NHEADS * 1024 * 4;
  const size_t per_g    = (size_t)NHEADS * 1024 * 4;
  const size_t per_b = per_pre * 2 + per_ssq + per_attn + per_g;

  int bc = 4;
  while (bc > 1 && per_b * (size_t)bc > ws_size) bc >>= 1;

  char* p = (char*)d_ws;
  unsigned short* pre = (unsigned short*)p; p += per_pre * bc;
  unsigned short* dwo = (unsigned short*)p; p += per_pre * bc;
  float* ssq   = (float*)p; p += per_ssq * bc;
  float* attn  = (float*)p; p += per_attn * bc;
  float* g     = (float*)p; p += per_g * bc;
  unsigned short* tbuf = pre;

  for (int b0 = 0; b0 < 4; b0 += bc) {
    k1_qkv_mfma<<<dim3(128, 3, bc), 256, 0, stream>>>(x, qkv_w, qkv_b, pre, b0);
    k2_dw<<<dim3(C3, 8, bc), 256, 0, stream>>>(pre, dw_w, dw_b, dwo);
    hipMemsetAsync(ssq, 0, per_ssq * bc, stream);
    hipMemsetAsync(g, 0, per_g * bc, stream);
    k3_gram<<<dim3(24, NHEADS, bc), 256, 0, stream>>>(dwo, g, ssq);
    k4b_softmax<<<dim3(NHEADS, bc), 64, 0, stream>>>(g, ssq, temp, attn);
    k5a_attnv<<<dim3(384, bc), 256, 0, stream>>>(dwo, attn, tbuf);
    k5b_proj<<<dim3(128, bc), 256, 0, stream>>>(tbuf, proj_w, proj_b, out, b0);
  }
}

// Round 14
// 232.754 us; speedup vs baseline: 1.0003x; 1.0003x over previous
//
#include <hip/hip_runtime.h>

#define CC 96
#define C3 288
#define HH 256
#define WW 256
#define HWC 65536
#define NHEADS 8
#define W2 32

typedef __bf16 bf16x8 __attribute__((ext_vector_type(8)));
typedef float f32x4 __attribute__((ext_vector_type(4)));
typedef unsigned short us8v __attribute__((ext_vector_type(8)));

__device__ __forceinline__ float bf2f(unsigned short u) {
  return __uint_as_float(((unsigned)u) << 16);
}
__device__ __forceinline__ unsigned short f2bf(float f) {
  unsigned u = __float_as_uint(f);
  unsigned r = u + 0x7fffu + ((u >> 16) & 1u);
  return (unsigned short)(r >> 16);
}

// K1 v4c: round-10 v4b structure; grid reordered to (3 groups, 128 tiles, bc)
// so the 3 same-tile blocks are dispatch-adjacent and share x via L2/L3.
__global__ __launch_bounds__(256, 4) void k1_qkv_mfma(
    const float* __restrict__ x, const float* __restrict__ qw,
    const float* __restrict__ qb, unsigned short* __restrict__ pre, int b0)
{
  __shared__ __align__(16) unsigned short As2[2][64 * 106];
  const int t = threadIdx.x;
  const int o0 = blockIdx.x * 96;     // qkv group (fastest-varying)
  const int bz = blockIdx.z;
  const float* xb = x + (size_t)(b0 + bz) * CC * HWC;

  const int wave = t >> 6, lane = t & 63;
  const int wm = wave & 1, wn = wave >> 1;
  const int row = lane & 15, kg = lane >> 4;

  bf16x8 bfr[3][3];
  float bias[3];
#pragma unroll
  for (int nt = 0; nt < 3; ++nt) {
    int ocl = wn * 48 + nt * 16 + row;
    bias[nt] = qb[o0 + ocl];
#pragma unroll
    for (int kk = 0; kk < 3; ++kk) {
      const float* wp = qw + (size_t)(o0 + ocl) * 96 + kk * 32 + kg * 8;
      float4 w0 = *reinterpret_cast<const float4*>(wp);
      float4 w1 = *reinterpret_cast<const float4*>(wp + 4);
      us8v u;
      u[0] = f2bf(w0.x); u[1] = f2bf(w0.y); u[2] = f2bf(w0.z); u[3] = f2bf(w0.w);
      u[4] = f2bf(w1.x); u[5] = f2bf(w1.y); u[6] = f2bf(w1.z); u[7] = f2bf(w1.w);
      bfr[kk][nt] = *reinterpret_cast<bf16x8*>(&u);
    }
  }

  int sic[3], sp4[3];
#pragma unroll
  for (int r = 0; r < 3; ++r) {
    int lin = r * 256 + t;
    sic[r] = lin >> 4;
    sp4[r] = (lin & 15) * 4;
  }

  int p0 = blockIdx.y * 512;
  float4 va0[3], va1[3];
#pragma unroll
  for (int r = 0; r < 3; ++r) {
    va0[r] = *reinterpret_cast<const float4*>(xb + (size_t)(2 * sic[r]) * HWC + p0 + sp4[r]);
    va1[r] = *reinterpret_cast<const float4*>(xb + (size_t)(2 * sic[r] + 1) * HWC + p0 + sp4[r]);
  }

  for (int i = 0; i < 8; ++i) {
    unsigned short* Ac = As2[i & 1];
#pragma unroll
    for (int r = 0; r < 3; ++r) {
      float a0[4] = {va0[r].x, va0[r].y, va0[r].z, va0[r].w};
      float a1[4] = {va1[r].x, va1[r].y, va1[r].z, va1[r].w};
#pragma unroll
      for (int j = 0; j < 4; ++j) {
        unsigned pk = (unsigned)f2bf(a0[j]) | ((unsigned)f2bf(a1[j]) << 16);
        *reinterpret_cast<unsigned*>(&Ac[(sp4[r] + j) * 106 + 2 * sic[r]]) = pk;
      }
    }
    if (i < 7) {
      int p0n = p0 + 64;
#pragma unroll
      for (int r = 0; r < 3; ++r) {
        va0[r] = *reinterpret_cast<const float4*>(xb + (size_t)(2 * sic[r]) * HWC + p0n + sp4[r]);
        va1[r] = *reinterpret_cast<const float4*>(xb + (size_t)(2 * sic[r] + 1) * HWC + p0n + sp4[r]);
      }
    }
    __syncthreads();

    f32x4 acc[2][3];
#pragma unroll
    for (int mt = 0; mt < 2; ++mt)
#pragma unroll
      for (int nt = 0; nt < 3; ++nt) acc[mt][nt] = (f32x4){0.f, 0.f, 0.f, 0.f};
#pragma unroll
    for (int kk = 0; kk < 3; ++kk) {
      bf16x8 a[2];
#pragma unroll
      for (int mt = 0; mt < 2; ++mt)
        a[mt] = *reinterpret_cast<const bf16x8*>(
            &Ac[(wm * 32 + mt * 16 + row) * 106 + kk * 32 + kg * 8]);
#pragma unroll
      for (int mt = 0; mt < 2; ++mt)
#pragma unroll
        for (int nt = 0; nt < 3; ++nt)
          acc[mt][nt] = __builtin_amdgcn_mfma_f32_16x16x32_bf16(
              a[mt], bfr[kk][nt], acc[mt][nt], 0, 0, 0);
    }
    __syncthreads();

    unsigned short* tD = (unsigned short*)As2;   // [96][72]
#pragma unroll
    for (int nt = 0; nt < 3; ++nt) {
      int ocl = wn * 48 + nt * 16 + row;
      float bv = bias[nt];
#pragma unroll
      for (int mt = 0; mt < 2; ++mt) {
        int pxl = wm * 32 + mt * 16 + kg * 4;
        f32x4 v = acc[mt][nt];
        unsigned pk0 = (unsigned)f2bf(v[0] + bv) | ((unsigned)f2bf(v[1] + bv) << 16);
        unsigned pk1 = (unsigned)f2bf(v[2] + bv) | ((unsigned)f2bf(v[3] + bv) << 16);
        *reinterpret_cast<unsigned*>(&tD[ocl * 72 + pxl]) = pk0;
        *reinterpret_cast<unsigned*>(&tD[ocl * 72 + pxl + 2]) = pk1;
      }
    }
    __syncthreads();
    unsigned short* preb = pre + ((size_t)bz * C3 + o0) * HWC + p0;
#pragma unroll
    for (int r = 0; r < 3; ++r) {
      int lin = r * 256 + t;
      int oc = lin >> 3, ch = lin & 7;
      us8v v = *reinterpret_cast<const us8v*>(&tD[oc * 72 + ch * 8]);
      *reinterpret_cast<us8v*>(preb + (size_t)oc * HWC + ch * 8) = v;
    }
    __syncthreads();
    p0 += 64;
  }
}

// K2: depthwise 3x3 + bias, LDS-free register-rolling. grid (288, 8, bc).
__global__ __launch_bounds__(256) void k2_dw(
    const unsigned short* __restrict__ pre, const float* __restrict__ dww,
    const float* __restrict__ dwb, unsigned short* __restrict__ dwo)
{
  const int t = threadIdx.x;
  const int c3 = blockIdx.x;
  const int hb = blockIdx.y;
  const int bz = blockIdx.z;
  const size_t choff = ((size_t)bz * C3 + c3) * HWC;
  const int team = t >> 5, tl = t & 31;
  const int h0 = hb * 32 + team * 4;

  us8v rin[6];
#pragma unroll
  for (int r = 0; r < 6; ++r) {
    int hh = h0 - 1 + r;
    if (hh >= 0 && hh < HH)
      rin[r] = *reinterpret_cast<const us8v*>(pre + choff + (size_t)hh * WW + tl * 8);
    else
      rin[r] = (us8v){0, 0, 0, 0, 0, 0, 0, 0};
  }

  float wg[9];
#pragma unroll
  for (int i = 0; i < 9; ++i) wg[i] = dww[c3 * 9 + i];
  const float bias = dwb[c3];

  float f[6][8];
  float lf[6], rt[6];
#pragma unroll
  for (int r = 0; r < 6; ++r) {
#pragma unroll
    for (int j = 0; j < 8; ++j) f[r][j] = bf2f(rin[r][j]);
    float l = __shfl_up(f[r][7], 1, 32);
    float rr = __shfl_down(f[r][0], 1, 32);
    lf[r] = (tl == 0) ? 0.f : l;
    rt[r] = (tl == 31) ? 0.f : rr;
  }

#pragma unroll
  for (int orow = 0; orow < 4; ++orow) {
    float o[8];
#pragma unroll
    for (int j = 0; j < 8; ++j) o[j] = bias;
#pragma unroll
    for (int k = 0; k < 3; ++k) {
      const int r = orow + k;
      const float w0 = wg[k * 3 + 0], w1 = wg[k * 3 + 1], w2 = wg[k * 3 + 2];
      o[0] = fmaf(lf[r], w0, fmaf(f[r][0], w1, fmaf(f[r][1], w2, o[0])));
#pragma unroll
      for (int j = 1; j < 7; ++j)
        o[j] = fmaf(f[r][j - 1], w0, fmaf(f[r][j], w1, fmaf(f[r][j + 1], w2, o[j])));
      o[7] = fmaf(f[r][6], w0, fmaf(f[r][7], w1, fmaf(rt[r], w2, o[7])));
    }
    us8v u;
#pragma unroll
    for (int j = 0; j < 8; ++j) u[j] = f2bf(o[j]);
    *reinterpret_cast<us8v*>((unsigned short*)dwo + choff + (size_t)(h0 + orow) * WW + tl * 8) = u;
  }
}

// K3 v4: Gram via bf16 MFMA; partial Gram STORED per cg0 (no g atomics);
// sumsq via atomics. grid (24, 8, bc), block 256 (4 waves).
__global__ __launch_bounds__(256, 4) void k3_gram(
    const unsigned short* __restrict__ dwo, float* __restrict__ gpart,
    float* __restrict__ ssq)
{
  __shared__ __align__(16) unsigned short qT[32 * 264];
  __shared__ __align__(16) unsigned short kT[32 * 264];
  const int t = threadIdx.x;
  const int cg0 = blockIdx.x;
  const int head = blockIdx.y, bz = blockIdx.z;
  const int lane = t & 63, wave = t >> 6;
  const int mt = wave & 1, nt = wave >> 1;
  const int l15 = lane & 15, l4 = lane >> 4;
  const int cg = t & 7;
  int rp[4];
#pragma unroll
  for (int r = 0; r < 4; ++r) rp[r] = (r * 256 + t) >> 3;

  const unsigned short* qbase = dwo + ((size_t)bz * C3 + cg0 * 4) * HWC + head * W2;
  const unsigned short* kbase = qbase + (size_t)CC * HWC;

  ushort4 qa[4], qb_[4], ka[4], kb_[4];
#pragma unroll
  for (int r = 0; r < 4; ++r) {
    qa[r] = *reinterpret_cast<const ushort4*>(qbase + (size_t)(2 * rp[r]) * WW + cg * 4);
    qb_[r] = *reinterpret_cast<const ushort4*>(qbase + (size_t)(2 * rp[r] + 1) * WW + cg * 4);
    ka[r] = *reinterpret_cast<const ushort4*>(kbase + (size_t)(2 * rp[r]) * WW + cg * 4);
    kb_[r] = *reinterpret_cast<const ushort4*>(kbase + (size_t)(2 * rp[r] + 1) * WW + cg * 4);
  }

  f32x4 acc = (f32x4){0.f, 0.f, 0.f, 0.f};
  float ssum_q = 0.f, ssum_k = 0.f;

  for (int cc = 0; cc < 4; ++cc) {
#pragma unroll
    for (int r = 0; r < 4; ++r) {
      unsigned short aq0[4] = {qa[r].x, qa[r].y, qa[r].z, qa[r].w};
      unsigned short aq1[4] = {qb_[r].x, qb_[r].y, qb_[r].z, qb_[r].w};
      unsigned short ak0[4] = {ka[r].x, ka[r].y, ka[r].z, ka[r].w};
      unsigned short ak1[4] = {kb_[r].x, kb_[r].y, kb_[r].z, kb_[r].w};
#pragma unroll
      for (int j = 0; j < 4; ++j) {
        int dwi = (cg * 4 + j) * 132 + rp[r];
        *(reinterpret_cast<unsigned*>(qT) + dwi) =
            (unsigned)aq0[j] | ((unsigned)aq1[j] << 16);
        *(reinterpret_cast<unsigned*>(kT) + dwi) =
            (unsigned)ak0[j] | ((unsigned)ak1[j] << 16);
      }
    }
    if (cc < 3) {
      const unsigned short* qn = qbase + (size_t)(cc + 1) * HWC;
      const unsigned short* kn = kbase + (size_t)(cc + 1) * HWC;
#pragma unroll
      for (int r = 0; r < 4; ++r) {
        qa[r] = *reinterpret_cast<const ushort4*>(qn + (size_t)(2 * rp[r]) * WW + cg * 4);
        qb_[r] = *reinterpret_cast<const ushort4*>(qn + (size_t)(2 * rp[r] + 1) * WW + cg * 4);
        ka[r] = *reinterpret_cast<const ushort4*>(kn + (size_t)(2 * rp[r]) * WW + cg * 4);
        kb_[r] = *reinterpret_cast<const ushort4*>(kn + (size_t)(2 * rp[r] + 1) * WW + cg * 4);
      }
    }
    __builtin_amdgcn_sched_barrier(0);
    __syncthreads();
#pragma unroll
    for (int kk = 0; kk < 8; ++kk) {
      bf16x8 a = *reinterpret_cast<const bf16x8*>(
          &qT[(mt * 16 + l15) * 264 + kk * 32 + l4 * 8]);
      bf16x8 b = *reinterpret_cast<const bf16x8*>(
          &kT[(nt * 16 + l15) * 264 + kk * 32 + l4 * 8]);
      acc = __builtin_amdgcn_mfma_f32_16x16x32_bf16(a, b, acc, 0, 0, 0);
    }
    {
      const int i = t & 31, seg = t >> 5;
#pragma unroll
      for (int m = 0; m < 4; ++m) {
        us8v vq = *reinterpret_cast<const us8v*>(&qT[i * 264 + seg * 32 + m * 8]);
        us8v vk = *reinterpret_cast<const us8v*>(&kT[i * 264 + seg * 32 + m * 8]);
#pragma unroll
        for (int e = 0; e < 8; ++e) {
          float fq = bf2f(vq[e]), fk = bf2f(vk[e]);
          ssum_q = fmaf(fq, fq, ssum_q);
          ssum_k = fmaf(fk, fk, ssum_k);
        }
      }
    }
    __syncthreads();
  }

  // partial Gram store (no atomics): slice (bz, head, cg0)
  float* gp = gpart + (((size_t)bz * NHEADS + head) * 24 + cg0) * 1024;
#pragma unroll
  for (int reg = 0; reg < 4; ++reg)
    gp[(nt * 16 + l15) * 32 + mt * 16 + l4 * 4 + reg] = acc[reg];

  float* red = reinterpret_cast<float*>(qT);
  red[t] = ssum_q;
  red[256 + t] = ssum_k;
  __syncthreads();
  if (t < 32) {
    float sq = 0.f, sk = 0.f;
#pragma unroll
    for (int p = 0; p < 8; ++p) { sq += red[t + 32 * p]; sk += red[256 + t + 32 * p]; }
    atomicAdd(&ssq[(size_t)bz * 512 + head * W2 + t], sq);
    atomicAdd(&ssq[(size_t)bz * 512 + 256 + head * W2 + t], sk);
  }
}

// K4b v2: reduce gpart over 24 cg + normalize + temperature + softmax.
// grid (8, bc), block 256.
__global__ __launch_bounds__(256) void k4b_softmax(
    const float* __restrict__ gpart, const float* __restrict__ ssq,
    const float* __restrict__ temp, float* __restrict__ attn)
{
  __shared__ float lg[1024];
  const int t = threadIdx.x;
  const int head = blockIdx.x, bz = blockIdx.y;
  const float* gp = gpart + ((size_t)bz * NHEADS + head) * 24 * 1024;
  float4 s = make_float4(0.f, 0.f, 0.f, 0.f);
#pragma unroll 4
  for (int cg = 0; cg < 24; ++cg) {
    float4 v = *reinterpret_cast<const float4*>(gp + cg * 1024 + t * 4);
    s.x += v.x; s.y += v.y; s.z += v.z; s.w += v.w;
  }
  *reinterpret_cast<float4*>(&lg[t * 4]) = s;
  __syncthreads();
  if (t < 32) {
    const int i = t;
    const float* sq_ = ssq + (size_t)bz * 512 + head * W2;
    const float* sk_ = ssq + (size_t)bz * 512 + 256 + head * W2;
    float invq = 1.f / fmaxf(sqrtf(sq_[i]), 1e-12f);
    float tpq = temp[head] * invq;
    float rowv[32];
    float m = -1e30f;
#pragma unroll
    for (int j = 0; j < 32; ++j) {
      float invk = 1.f / fmaxf(sqrtf(sk_[j]), 1e-12f);
      float v = lg[j * 32 + i] * tpq * invk;
      rowv[j] = v;
      m = fmaxf(m, v);
    }
    float ssum = 0;
#pragma unroll
    for (int j = 0; j < 32; ++j) { rowv[j] = expf(rowv[j] - m); ssum += rowv[j]; }
    float inv = 1.f / ssum;
    float* ap = attn + ((size_t)bz * NHEADS + head) * 1024 + i * 32;
#pragma unroll
    for (int j = 0; j < 32; ++j) ap[j] = rowv[j] * inv;
  }
}

// K5a: t = attn @ v via MFMA. grid (384, bc), block 256 (4 waves).
__global__ __launch_bounds__(256) void k5a_attnv(
    const unsigned short* __restrict__ dwo, const float* __restrict__ attn,
    unsigned short* __restrict__ tbuf)
{
  __shared__ __align__(16) unsigned short vsm[64 * 264];
  __shared__ __align__(16) unsigned short atn_s[256 * 36];
  const int t = threadIdx.x;
  const int tile = blockIdx.x;
  const int bz = blockIdx.y;
  const size_t R0 = (size_t)tile * 64;
  const unsigned short* vsrc = dwo + ((size_t)bz * C3 + 2 * CC) * HWC + R0 * 256;

  us8v vv[8];
#pragma unroll
  for (int j = 0; j < 8; ++j)
    vv[j] = *reinterpret_cast<const us8v*>(vsrc + (size_t)(j * 256 + t) * 8);
  float4 av[8];
  {
    const float* ap = attn + (size_t)bz * 8192 + t * 32;
#pragma unroll
    for (int k = 0; k < 8; ++k)
      av[k] = *reinterpret_cast<const float4*>(ap + k * 4);
  }
  __builtin_amdgcn_sched_barrier(0);
#pragma unroll
  for (int j = 0; j < 8; ++j) {
    int n = j * 256 + t;
    int row = n >> 5, c8 = n & 31;
    *reinterpret_cast<us8v*>(&vsm[row * 264 + c8 * 8]) = vv[j];
  }
#pragma unroll
  for (int k = 0; k < 8; ++k) {
    ushort4 u;
    u.x = f2bf(av[k].x); u.y = f2bf(av[k].y); u.z = f2bf(av[k].z); u.w = f2bf(av[k].w);
    *reinterpret_cast<ushort4*>(&atn_s[t * 36 + k * 4]) = u;
  }
  __syncthreads();

  const int wave = t >> 6, lane = t & 63;
  const int mrow = lane & 15, kg = lane >> 4;

  bf16x8 a[8], b[16];
#pragma unroll
  for (int hd = 0; hd < 8; ++hd)
    a[hd] = *reinterpret_cast<const bf16x8*>(
        &vsm[(wave * 16 + mrow) * 264 + hd * 32 + kg * 8]);
#pragma unroll
  for (int hd = 0; hd < 8; ++hd)
#pragma unroll
    for (int it = 0; it < 2; ++it)
      b[hd * 2 + it] = *reinterpret_cast<const bf16x8*>(
          &atn_s[(hd * 32 + it * 16 + mrow) * 36 + kg * 8]);

  f32x4 acc[16];
#pragma unroll
  for (int q = 0; q < 16; ++q) acc[q] = (f32x4){0.f, 0.f, 0.f, 0.f};
#pragma unroll
  for (int hd = 0; hd < 8; ++hd)
#pragma unroll
    for (int it = 0; it < 2; ++it)
      acc[hd * 2 + it] = __builtin_amdgcn_mfma_f32_16x16x32_bf16(
          a[hd], b[hd * 2 + it], acc[hd * 2 + it], 0, 0, 0);
  __syncthreads();

#pragma unroll
  for (int hd = 0; hd < 8; ++hd)
#pragma unroll
    for (int it = 0; it < 2; ++it) {
      f32x4 v = acc[hd * 2 + it];
      int col = hd * 32 + it * 16 + mrow;
#pragma unroll
      for (int r = 0; r < 4; ++r)
        vsm[(wave * 16 + kg * 4 + r) * 264 + col] = f2bf(v[r]);
    }
  unsigned short* tdst = tbuf + (size_t)bz * CC * HWC + R0 * 256;
#pragma unroll
  for (int k = 0; k < 8; ++k) {
    int n = k * 64 + lane;
    int rloc = n >> 5, c8 = n & 31;
    us8v v = *reinterpret_cast<const us8v*>(&vsm[(wave * 16 + rloc) * 264 + c8 * 8]);
    *reinterpret_cast<us8v*>(tdst + ((size_t)(wave * 16 + rloc)) * 256 + c8 * 8) = v;
  }
}

// K5b v2b (known-good): out = proj(t) + pb via MFMA. 64-px tiles x 8.
__global__ __launch_bounds__(256, 4) void k5b_proj(
    const unsigned short* __restrict__ tbuf, const float* __restrict__ pw,
    const float* __restrict__ pb, float* __restrict__ out, int b0)
{
  __shared__ __align__(16) unsigned short As2[2][64 * 106];
  const int t = threadIdx.x;
  const int bz = blockIdx.y;
  const unsigned short* tb = tbuf + (size_t)bz * CC * HWC;

  const int wave = t >> 6, lane = t & 63;
  const int wm = wave & 1, wn = wave >> 1;
  const int row = lane & 15, kg = lane >> 4;

  bf16x8 bfr[3][3];
  float bias[3];
#pragma unroll
  for (int nt = 0; nt < 3; ++nt) {
    int ocl = wn * 48 + nt * 16 + row;
    bias[nt] = pb[ocl];
#pragma unroll
    for (int kk = 0; kk < 3; ++kk) {
      const float* wp = pw + (size_t)ocl * 96 + kk * 32 + kg * 8;
      float4 w0 = *reinterpret_cast<const float4*>(wp);
      float4 w1 = *reinterpret_cast<const float4*>(wp + 4);
      us8v u;
      u[0] = f2bf(w0.x); u[1] = f2bf(w0.y); u[2] = f2bf(w0.z); u[3] = f2bf(w0.w);
      u[4] = f2bf(w1.x); u[5] = f2bf(w1.y); u[6] = f2bf(w1.z); u[7] = f2bf(w1.w);
      bfr[kk][nt] = *reinterpret_cast<bf16x8*>(&u);
    }
  }

  int sic[3], sp4[3];
#pragma unroll
  for (int r = 0; r < 3; ++r) {
    int lin = r * 256 + t;
    sic[r] = lin >> 4;
    sp4[r] = (lin & 15) * 4;
  }

  int p0 = blockIdx.x * 512;
  ushort4 ua0[3], ua1[3];
#pragma unroll
  for (int r = 0; r < 3; ++r) {
    ua0[r] = *reinterpret_cast<const ushort4*>(tb + (size_t)(2 * sic[r]) * HWC + p0 + sp4[r]);
    ua1[r] = *reinterpret_cast<const ushort4*>(tb + (size_t)(2 * sic[r] + 1) * HWC + p0 + sp4[r]);
  }

  for (int i = 0; i < 8; ++i) {
    unsigned short* Ac = As2[i & 1];
#pragma unroll
    for (int r = 0; r < 3; ++r) {
      unsigned short a0[4] = {ua0[r].x, ua0[r].y, ua0[r].z, ua0[r].w};
      unsigned short a1[4] = {ua1[r].x, ua1[r].y, ua1[r].z, ua1[r].w};
#pragma unroll
      for (int j = 0; j < 4; ++j) {
        unsigned pk = (unsigned)a0[j] | ((unsigned)a1[j] << 16);
        *reinterpret_cast<unsigned*>(&Ac[(sp4[r] + j) * 106 + 2 * sic[r]]) = pk;
      }
    }
    if (i < 7) {
      int p0n = p0 + 64;
#pragma unroll
      for (int r = 0; r < 3; ++r) {
        ua0[r] = *reinterpret_cast<const ushort4*>(tb + (size_t)(2 * sic[r]) * HWC + p0n + sp4[r]);
        ua1[r] = *reinterpret_cast<const ushort4*>(tb + (size_t)(2 * sic[r] + 1) * HWC + p0n + sp4[r]);
      }
    }
    __syncthreads();

    f32x4 acc[2][3];
#pragma unroll
    for (int mt = 0; mt < 2; ++mt)
#pragma unroll
      for (int nt = 0; nt < 3; ++nt) acc[mt][nt] = (f32x4){0.f, 0.f, 0.f, 0.f};
#pragma unroll
    for (int kk = 0; kk < 3; ++kk) {
      bf16x8 a[2];
#pragma unroll
      for (int mt = 0; mt < 2; ++mt)
        a[mt] = *reinterpret_cast<const bf16x8*>(
            &Ac[(wm * 32 + mt * 16 + row) * 106 + kk * 32 + kg * 8]);
#pragma unroll
      for (int mt = 0; mt < 2; ++mt)
#pragma unroll
        for (int nt = 0; nt < 3; ++nt)
          acc[mt][nt] = __builtin_amdgcn_mfma_f32_16x16x32_bf16(
              a[mt], bfr[kk][nt], acc[mt][nt], 0, 0, 0);
    }
    __syncthreads();

    float* tD = (float*)As2;   // [96][68] fp32, spans both buffers
#pragma unroll
    for (int nt = 0; nt < 3; ++nt) {
      int ocl = wn * 48 + nt * 16 + row;
      float bv = bias[nt];
#pragma unroll
      for (int mt = 0; mt < 2; ++mt) {
        int pxl = wm * 32 + mt * 16 + kg * 4;
        f32x4 v = acc[mt][nt];
        float4 w = make_float4(v[0] + bv, v[1] + bv, v[2] + bv, v[3] + bv);
        *reinterpret_cast<float4*>(&tD[ocl * 68 + pxl]) = w;
      }
    }
    __syncthreads();
    float* ob = out + (size_t)(b0 + bz) * CC * HWC + p0;
#pragma unroll
    for (int r = 0; r < 6; ++r) {
      int lin = r * 256 + t;
      int o = lin >> 4, p4 = (lin & 15) * 4;
      float4 v = *reinterpret_cast<const float4*>(&tD[o * 68 + p4]);
      *reinterpret_cast<float4*>(ob + (size_t)o * HWC + p4) = v;
    }
    __syncthreads();
    p0 += 64;
  }
}

extern "C" void kernel_launch(void* const* d_in, const int* in_sizes, int n_in,
                              void* d_out, int out_size, void* d_ws, size_t ws_size,
                              hipStream_t stream)
{
  const float* x      = (const float*)d_in[0];
  const float* qkv_w  = (const float*)d_in[1];
  const float* qkv_b  = (const float*)d_in[2];
  const float* dw_w   = (const float*)d_in[3];
  const float* dw_b   = (const float*)d_in[4];
  const float* proj_w = (const float*)d_in[5];
  const float* proj_b = (const float*)d_in[6];
  const float* temp   = (const float*)d_in[7];
  float* out = (float*)d_out;

  const size_t per_pre   = (size_t)C3 * HWC * 2;
  const size_t per_ssq   = (size_t)2 * 256 * 4;
  const size_t per_attn  = (size_t)NHEADS * 1024 * 4;
  const size_t per_gpart = (size_t)NHEADS * 24 * 1024 * 4;
  const size_t per_b = per_pre * 2 + per_ssq + per_attn + per_gpart;

  int bc = 4;
  while (bc > 1 && per_b * (size_t)bc > ws_size) bc >>= 1;

  char* p = (char*)d_ws;
  unsigned short* pre = (unsigned short*)p; p += per_pre * bc;
  unsigned short* dwo = (unsigned short*)p; p += per_pre * bc;
  float* ssq   = (float*)p; p += per_ssq * bc;
  float* attn  = (float*)p; p += per_attn * bc;
  float* gpart = (float*)p; p += per_gpart * bc;
  unsigned short* tbuf = pre;

  for (int b0 = 0; b0 < 4; b0 += bc) {
    k1_qkv_mfma<<<dim3(3, 128, bc), 256, 0, stream>>>(x, qkv_w, qkv_b, pre, b0);
    k2_dw<<<dim3(C3, 8, bc), 256, 0, stream>>>(pre, dw_w, dw_b, dwo);
    hipMemsetAsync(ssq, 0, per_ssq * bc, stream);
    k3_gram<<<dim3(24, NHEADS, bc), 256, 0, stream>>>(dwo, gpart, ssq);
    k4b_softmax<<<dim3(NHEADS, bc), 256, 0, stream>>>(gpart, ssq, temp, attn);
    k5a_attnv<<<dim3(384, bc), 256, 0, stream>>>(dwo, attn, tbuf);
    k5b_proj<<<dim3(128, bc), 256, 0, stream>>>(tbuf, proj_w, proj_b, out, b0);
  }
}

// Round 15
// 223.168 us; speedup vs baseline: 1.0433x; 1.0430x over previous
//
#include <hip/hip_runtime.h>

#define CC 96
#define C3 288
#define HH 256
#define WW 256
#define HWC 65536
#define NHEADS 8
#define W2 32

typedef __bf16 bf16x8 __attribute__((ext_vector_type(8)));
typedef float f32x4 __attribute__((ext_vector_type(4)));
typedef unsigned short us8v __attribute__((ext_vector_type(8)));

__device__ __forceinline__ float bf2f(unsigned short u) {
  return __uint_as_float(((unsigned)u) << 16);
}
__device__ __forceinline__ unsigned short f2bf(float f) {
  unsigned u = __float_as_uint(f);
  unsigned r = u + 0x7fffu + ((u >> 16) & 1u);
  return (unsigned short)(r >> 16);
}

// K1 v4b (round-10 exact): qkv conv1x1 via bf16 MFMA. 64-px tiles x 8,
// pipelined, 27KB LDS. grid (128, 3, bc): tile fastest -> same-x siblings
// are 128 apart in dispatch = same XCD (bid%8) -> L2-shared x.
__global__ __launch_bounds__(256, 4) void k1_qkv_mfma(
    const float* __restrict__ x, const float* __restrict__ qw,
    const float* __restrict__ qb, unsigned short* __restrict__ pre, int b0)
{
  __shared__ __align__(16) unsigned short As2[2][64 * 106];
  const int t = threadIdx.x;
  const int o0 = blockIdx.y * 96;
  const int bz = blockIdx.z;
  const float* xb = x + (size_t)(b0 + bz) * CC * HWC;

  const int wave = t >> 6, lane = t & 63;
  const int wm = wave & 1, wn = wave >> 1;
  const int row = lane & 15, kg = lane >> 4;

  bf16x8 bfr[3][3];
  float bias[3];
#pragma unroll
  for (int nt = 0; nt < 3; ++nt) {
    int ocl = wn * 48 + nt * 16 + row;
    bias[nt] = qb[o0 + ocl];
#pragma unroll
    for (int kk = 0; kk < 3; ++kk) {
      const float* wp = qw + (size_t)(o0 + ocl) * 96 + kk * 32 + kg * 8;
      float4 w0 = *reinterpret_cast<const float4*>(wp);
      float4 w1 = *reinterpret_cast<const float4*>(wp + 4);
      us8v u;
      u[0] = f2bf(w0.x); u[1] = f2bf(w0.y); u[2] = f2bf(w0.z); u[3] = f2bf(w0.w);
      u[4] = f2bf(w1.x); u[5] = f2bf(w1.y); u[6] = f2bf(w1.z); u[7] = f2bf(w1.w);
      bfr[kk][nt] = *reinterpret_cast<bf16x8*>(&u);
    }
  }

  int sic[3], sp4[3];
#pragma unroll
  for (int r = 0; r < 3; ++r) {
    int lin = r * 256 + t;
    sic[r] = lin >> 4;
    sp4[r] = (lin & 15) * 4;
  }

  int p0 = blockIdx.x * 512;
  float4 va0[3], va1[3];
#pragma unroll
  for (int r = 0; r < 3; ++r) {
    va0[r] = *reinterpret_cast<const float4*>(xb + (size_t)(2 * sic[r]) * HWC + p0 + sp4[r]);
    va1[r] = *reinterpret_cast<const float4*>(xb + (size_t)(2 * sic[r] + 1) * HWC + p0 + sp4[r]);
  }

  for (int i = 0; i < 8; ++i) {
    unsigned short* Ac = As2[i & 1];
#pragma unroll
    for (int r = 0; r < 3; ++r) {
      float a0[4] = {va0[r].x, va0[r].y, va0[r].z, va0[r].w};
      float a1[4] = {va1[r].x, va1[r].y, va1[r].z, va1[r].w};
#pragma unroll
      for (int j = 0; j < 4; ++j) {
        unsigned pk = (unsigned)f2bf(a0[j]) | ((unsigned)f2bf(a1[j]) << 16);
        *reinterpret_cast<unsigned*>(&Ac[(sp4[r] + j) * 106 + 2 * sic[r]]) = pk;
      }
    }
    if (i < 7) {
      int p0n = p0 + 64;
#pragma unroll
      for (int r = 0; r < 3; ++r) {
        va0[r] = *reinterpret_cast<const float4*>(xb + (size_t)(2 * sic[r]) * HWC + p0n + sp4[r]);
        va1[r] = *reinterpret_cast<const float4*>(xb + (size_t)(2 * sic[r] + 1) * HWC + p0n + sp4[r]);
      }
    }
    __syncthreads();

    f32x4 acc[2][3];
#pragma unroll
    for (int mt = 0; mt < 2; ++mt)
#pragma unroll
      for (int nt = 0; nt < 3; ++nt) acc[mt][nt] = (f32x4){0.f, 0.f, 0.f, 0.f};
#pragma unroll
    for (int kk = 0; kk < 3; ++kk) {
      bf16x8 a[2];
#pragma unroll
      for (int mt = 0; mt < 2; ++mt)
        a[mt] = *reinterpret_cast<const bf16x8*>(
            &Ac[(wm * 32 + mt * 16 + row) * 106 + kk * 32 + kg * 8]);
#pragma unroll
      for (int mt = 0; mt < 2; ++mt)
#pragma unroll
        for (int nt = 0; nt < 3; ++nt)
          acc[mt][nt] = __builtin_amdgcn_mfma_f32_16x16x32_bf16(
              a[mt], bfr[kk][nt], acc[mt][nt], 0, 0, 0);
    }
    __syncthreads();

    unsigned short* tD = (unsigned short*)As2;   // [96][72]
#pragma unroll
    for (int nt = 0; nt < 3; ++nt) {
      int ocl = wn * 48 + nt * 16 + row;
      float bv = bias[nt];
#pragma unroll
      for (int mt = 0; mt < 2; ++mt) {
        int pxl = wm * 32 + mt * 16 + kg * 4;
        f32x4 v = acc[mt][nt];
        unsigned pk0 = (unsigned)f2bf(v[0] + bv) | ((unsigned)f2bf(v[1] + bv) << 16);
        unsigned pk1 = (unsigned)f2bf(v[2] + bv) | ((unsigned)f2bf(v[3] + bv) << 16);
        *reinterpret_cast<unsigned*>(&tD[ocl * 72 + pxl]) = pk0;
        *reinterpret_cast<unsigned*>(&tD[ocl * 72 + pxl + 2]) = pk1;
      }
    }
    __syncthreads();
    unsigned short* preb = pre + ((size_t)bz * C3 + o0) * HWC + p0;
#pragma unroll
    for (int r = 0; r < 3; ++r) {
      int lin = r * 256 + t;
      int oc = lin >> 3, ch = lin & 7;
      us8v v = *reinterpret_cast<const us8v*>(&tD[oc * 72 + ch * 8]);
      *reinterpret_cast<us8v*>(preb + (size_t)oc * HWC + ch * 8) = v;
    }
    __syncthreads();
    p0 += 64;
  }
}

// K2: depthwise 3x3 + bias for q,k channels ONLY (0..191). Register-rolling.
// grid (192, 8, bc). In: pre (288-ch layout), out: dwo (192-ch layout).
__global__ __launch_bounds__(256) void k2_dw(
    const unsigned short* __restrict__ pre, const float* __restrict__ dww,
    const float* __restrict__ dwb, unsigned short* __restrict__ dwo)
{
  const int t = threadIdx.x;
  const int c3 = blockIdx.x;           // 0..191
  const int hb = blockIdx.y;
  const int bz = blockIdx.z;
  const size_t choff_in  = ((size_t)bz * C3 + c3) * HWC;
  const size_t choff_out = ((size_t)bz * 192 + c3) * HWC;
  const int team = t >> 5, tl = t & 31;
  const int h0 = hb * 32 + team * 4;

  us8v rin[6];
#pragma unroll
  for (int r = 0; r < 6; ++r) {
    int hh = h0 - 1 + r;
    if (hh >= 0 && hh < HH)
      rin[r] = *reinterpret_cast<const us8v*>(pre + choff_in + (size_t)hh * WW + tl * 8);
    else
      rin[r] = (us8v){0, 0, 0, 0, 0, 0, 0, 0};
  }

  float wg[9];
#pragma unroll
  for (int i = 0; i < 9; ++i) wg[i] = dww[c3 * 9 + i];
  const float bias = dwb[c3];

  float f[6][8];
  float lf[6], rt[6];
#pragma unroll
  for (int r = 0; r < 6; ++r) {
#pragma unroll
    for (int j = 0; j < 8; ++j) f[r][j] = bf2f(rin[r][j]);
    float l = __shfl_up(f[r][7], 1, 32);
    float rr = __shfl_down(f[r][0], 1, 32);
    lf[r] = (tl == 0) ? 0.f : l;
    rt[r] = (tl == 31) ? 0.f : rr;
  }

#pragma unroll
  for (int orow = 0; orow < 4; ++orow) {
    float o[8];
#pragma unroll
    for (int j = 0; j < 8; ++j) o[j] = bias;
#pragma unroll
    for (int k = 0; k < 3; ++k) {
      const int r = orow + k;
      const float w0 = wg[k * 3 + 0], w1 = wg[k * 3 + 1], w2 = wg[k * 3 + 2];
      o[0] = fmaf(lf[r], w0, fmaf(f[r][0], w1, fmaf(f[r][1], w2, o[0])));
#pragma unroll
      for (int j = 1; j < 7; ++j)
        o[j] = fmaf(f[r][j - 1], w0, fmaf(f[r][j], w1, fmaf(f[r][j + 1], w2, o[j])));
      o[7] = fmaf(f[r][6], w0, fmaf(f[r][7], w1, fmaf(rt[r], w2, o[7])));
    }
    us8v u;
#pragma unroll
    for (int j = 0; j < 8; ++j) u[j] = f2bf(o[j]);
    *reinterpret_cast<us8v*>((unsigned short*)dwo + choff_out + (size_t)(h0 + orow) * WW + tl * 8) = u;
  }
}

// K3 v4: Gram via bf16 MFMA; partial Gram stored per cg0; sumsq via atomics.
// dwo is 192-ch (q at 0..95, k at 96..191). grid (24, 8, bc).
__global__ __launch_bounds__(256, 4) void k3_gram(
    const unsigned short* __restrict__ dwo, float* __restrict__ gpart,
    float* __restrict__ ssq)
{
  __shared__ __align__(16) unsigned short qT[32 * 264];
  __shared__ __align__(16) unsigned short kT[32 * 264];
  const int t = threadIdx.x;
  const int cg0 = blockIdx.x;
  const int head = blockIdx.y, bz = blockIdx.z;
  const int lane = t & 63, wave = t >> 6;
  const int mt = wave & 1, nt = wave >> 1;
  const int l15 = lane & 15, l4 = lane >> 4;
  const int cg = t & 7;
  int rp[4];
#pragma unroll
  for (int r = 0; r < 4; ++r) rp[r] = (r * 256 + t) >> 3;

  const unsigned short* qbase = dwo + ((size_t)bz * 192 + cg0 * 4) * HWC + head * W2;
  const unsigned short* kbase = qbase + (size_t)CC * HWC;

  ushort4 qa[4], qb_[4], ka[4], kb_[4];
#pragma unroll
  for (int r = 0; r < 4; ++r) {
    qa[r] = *reinterpret_cast<const ushort4*>(qbase + (size_t)(2 * rp[r]) * WW + cg * 4);
    qb_[r] = *reinterpret_cast<const ushort4*>(qbase + (size_t)(2 * rp[r] + 1) * WW + cg * 4);
    ka[r] = *reinterpret_cast<const ushort4*>(kbase + (size_t)(2 * rp[r]) * WW + cg * 4);
    kb_[r] = *reinterpret_cast<const ushort4*>(kbase + (size_t)(2 * rp[r] + 1) * WW + cg * 4);
  }

  f32x4 acc = (f32x4){0.f, 0.f, 0.f, 0.f};
  float ssum_q = 0.f, ssum_k = 0.f;

  for (int cc = 0; cc < 4; ++cc) {
#pragma unroll
    for (int r = 0; r < 4; ++r) {
      unsigned short aq0[4] = {qa[r].x, qa[r].y, qa[r].z, qa[r].w};
      unsigned short aq1[4] = {qb_[r].x, qb_[r].y, qb_[r].z, qb_[r].w};
      unsigned short ak0[4] = {ka[r].x, ka[r].y, ka[r].z, ka[r].w};
      unsigned short ak1[4] = {kb_[r].x, kb_[r].y, kb_[r].z, kb_[r].w};
#pragma unroll
      for (int j = 0; j < 4; ++j) {
        int dwi = (cg * 4 + j) * 132 + rp[r];
        *(reinterpret_cast<unsigned*>(qT) + dwi) =
            (unsigned)aq0[j] | ((unsigned)aq1[j] << 16);
        *(reinterpret_cast<unsigned*>(kT) + dwi) =
            (unsigned)ak0[j] | ((unsigned)ak1[j] << 16);
      }
    }
    if (cc < 3) {
      const unsigned short* qn = qbase + (size_t)(cc + 1) * HWC;
      const unsigned short* kn = kbase + (size_t)(cc + 1) * HWC;
#pragma unroll
      for (int r = 0; r < 4; ++r) {
        qa[r] = *reinterpret_cast<const ushort4*>(qn + (size_t)(2 * rp[r]) * WW + cg * 4);
        qb_[r] = *reinterpret_cast<const ushort4*>(qn + (size_t)(2 * rp[r] + 1) * WW + cg * 4);
        ka[r] = *reinterpret_cast<const ushort4*>(kn + (size_t)(2 * rp[r]) * WW + cg * 4);
        kb_[r] = *reinterpret_cast<const ushort4*>(kn + (size_t)(2 * rp[r] + 1) * WW + cg * 4);
      }
    }
    __builtin_amdgcn_sched_barrier(0);
    __syncthreads();
#pragma unroll
    for (int kk = 0; kk < 8; ++kk) {
      bf16x8 a = *reinterpret_cast<const bf16x8*>(
          &qT[(mt * 16 + l15) * 264 + kk * 32 + l4 * 8]);
      bf16x8 b = *reinterpret_cast<const bf16x8*>(
          &kT[(nt * 16 + l15) * 264 + kk * 32 + l4 * 8]);
      acc = __builtin_amdgcn_mfma_f32_16x16x32_bf16(a, b, acc, 0, 0, 0);
    }
    {
      const int i = t & 31, seg = t >> 5;
#pragma unroll
      for (int m = 0; m < 4; ++m) {
        us8v vq = *reinterpret_cast<const us8v*>(&qT[i * 264 + seg * 32 + m * 8]);
        us8v vk = *reinterpret_cast<const us8v*>(&kT[i * 264 + seg * 32 + m * 8]);
#pragma unroll
        for (int e = 0; e < 8; ++e) {
          float fq = bf2f(vq[e]), fk = bf2f(vk[e]);
          ssum_q = fmaf(fq, fq, ssum_q);
          ssum_k = fmaf(fk, fk, ssum_k);
        }
      }
    }
    __syncthreads();
  }

  float* gp = gpart + (((size_t)bz * NHEADS + head) * 24 + cg0) * 1024;
#pragma unroll
  for (int reg = 0; reg < 4; ++reg)
    gp[(nt * 16 + l15) * 32 + mt * 16 + l4 * 4 + reg] = acc[reg];

  float* red = reinterpret_cast<float*>(qT);
  red[t] = ssum_q;
  red[256 + t] = ssum_k;
  __syncthreads();
  if (t < 32) {
    float sq = 0.f, sk = 0.f;
#pragma unroll
    for (int p = 0; p < 8; ++p) { sq += red[t + 32 * p]; sk += red[256 + t + 32 * p]; }
    atomicAdd(&ssq[(size_t)bz * 512 + head * W2 + t], sq);
    atomicAdd(&ssq[(size_t)bz * 512 + 256 + head * W2 + t], sk);
  }
}

// K4b v2: reduce gpart over 24 cg + normalize + temperature + softmax.
__global__ __launch_bounds__(256) void k4b_softmax(
    const float* __restrict__ gpart, const float* __restrict__ ssq,
    const float* __restrict__ temp, float* __restrict__ attn)
{
  __shared__ float lg[1024];
  const int t = threadIdx.x;
  const int head = blockIdx.x, bz = blockIdx.y;
  const float* gp = gpart + ((size_t)bz * NHEADS + head) * 24 * 1024;
  float4 s = make_float4(0.f, 0.f, 0.f, 0.f);
#pragma unroll 4
  for (int cg = 0; cg < 24; ++cg) {
    float4 v = *reinterpret_cast<const float4*>(gp + cg * 1024 + t * 4);
    s.x += v.x; s.y += v.y; s.z += v.z; s.w += v.w;
  }
  *reinterpret_cast<float4*>(&lg[t * 4]) = s;
  __syncthreads();
  if (t < 32) {
    const int i = t;
    const float* sq_ = ssq + (size_t)bz * 512 + head * W2;
    const float* sk_ = ssq + (size_t)bz * 512 + 256 + head * W2;
    float invq = 1.f / fmaxf(sqrtf(sq_[i]), 1e-12f);
    float tpq = temp[head] * invq;
    float rowv[32];
    float m = -1e30f;
#pragma unroll
    for (int j = 0; j < 32; ++j) {
      float invk = 1.f / fmaxf(sqrtf(sk_[j]), 1e-12f);
      float v = lg[j * 32 + i] * tpq * invk;
      rowv[j] = v;
      m = fmaxf(m, v);
    }
    float ssum = 0;
#pragma unroll
    for (int j = 0; j < 32; ++j) { rowv[j] = expf(rowv[j] - m); ssum += rowv[j]; }
    float inv = 1.f / ssum;
    float* ap = attn + ((size_t)bz * NHEADS + head) * 1024 + i * 32;
#pragma unroll
    for (int j = 0; j < 32; ++j) ap[j] = rowv[j] * inv;
  }
}

// K5a v2: dw(v) FUSED + attn @ v via MFMA. grid (384, bc), block 256.
// Reads pre v-channels directly; k2-style register-rolling dw -> vsm.
__global__ __launch_bounds__(256) void k5a_attnv(
    const unsigned short* __restrict__ pre, const float* __restrict__ dww,
    const float* __restrict__ dwb, const float* __restrict__ attn,
    unsigned short* __restrict__ tbuf)
{
  __shared__ __align__(16) unsigned short vsm[64 * 264];
  __shared__ __align__(16) unsigned short atn_s[256 * 36];
  const int t = threadIdx.x;
  const int tile = blockIdx.x;
  const int bz = blockIdx.y;
  const size_t R0 = (size_t)tile * 64;
  const int c = tile >> 2;                 // v channel 0..95
  const int h0 = (tile & 3) * 64;
  const unsigned short* vsrc = pre + ((size_t)bz * C3 + 2 * CC + c) * HWC;
  const int team = t >> 5, tl = t & 31;

  // attn loads (latency covered by dw work)
  float4 av[8];
  {
    const float* ap = attn + (size_t)bz * 8192 + t * 32;
#pragma unroll
    for (int k = 0; k < 8; ++k)
      av[k] = *reinterpret_cast<const float4*>(ap + k * 4);
  }

  float wg[9];
#pragma unroll
  for (int i = 0; i < 9; ++i) wg[i] = dww[(2 * CC + c) * 9 + i];
  const float vbias = dwb[2 * CC + c];

  // dw in registers: team owns 8 output rows, 2 passes of 4
#pragma unroll
  for (int p = 0; p < 2; ++p) {
    const int hb = h0 + team * 8 + p * 4;      // output rows hb..hb+3
    us8v rin[6];
#pragma unroll
    for (int r = 0; r < 6; ++r) {
      int hh = hb - 1 + r;
      if (hh >= 0 && hh < HH)
        rin[r] = *reinterpret_cast<const us8v*>(vsrc + (size_t)hh * WW + tl * 8);
      else
        rin[r] = (us8v){0, 0, 0, 0, 0, 0, 0, 0};
    }
    float f[6][8], lf[6], rt[6];
#pragma unroll
    for (int r = 0; r < 6; ++r) {
#pragma unroll
      for (int j = 0; j < 8; ++j) f[r][j] = bf2f(rin[r][j]);
      float l = __shfl_up(f[r][7], 1, 32);
      float rr = __shfl_down(f[r][0], 1, 32);
      lf[r] = (tl == 0) ? 0.f : l;
      rt[r] = (tl == 31) ? 0.f : rr;
    }
#pragma unroll
    for (int orow = 0; orow < 4; ++orow) {
      float o[8];
#pragma unroll
      for (int j = 0; j < 8; ++j) o[j] = vbias;
#pragma unroll
      for (int k = 0; k < 3; ++k) {
        const int r = orow + k;
        const float w0 = wg[k * 3 + 0], w1 = wg[k * 3 + 1], w2 = wg[k * 3 + 2];
        o[0] = fmaf(lf[r], w0, fmaf(f[r][0], w1, fmaf(f[r][1], w2, o[0])));
#pragma unroll
        for (int j = 1; j < 7; ++j)
          o[j] = fmaf(f[r][j - 1], w0, fmaf(f[r][j], w1, fmaf(f[r][j + 1], w2, o[j])));
        o[7] = fmaf(f[r][6], w0, fmaf(f[r][7], w1, fmaf(rt[r], w2, o[7])));
      }
      us8v u;
#pragma unroll
      for (int j = 0; j < 8; ++j) u[j] = f2bf(o[j]);
      int rl = team * 8 + p * 4 + orow;        // 0..63
      *reinterpret_cast<us8v*>(&vsm[rl * 264 + tl * 8]) = u;
    }
  }
#pragma unroll
  for (int k = 0; k < 8; ++k) {
    ushort4 u;
    u.x = f2bf(av[k].x); u.y = f2bf(av[k].y); u.z = f2bf(av[k].z); u.w = f2bf(av[k].w);
    *reinterpret_cast<ushort4*>(&atn_s[t * 36 + k * 4]) = u;
  }
  __syncthreads();

  const int wave = t >> 6, lane = t & 63;
  const int mrow = lane & 15, kg = lane >> 4;

  bf16x8 a[8], b[16];
#pragma unroll
  for (int hd = 0; hd < 8; ++hd)
    a[hd] = *reinterpret_cast<const bf16x8*>(
        &vsm[(wave * 16 + mrow) * 264 + hd * 32 + kg * 8]);
#pragma unroll
  for (int hd = 0; hd < 8; ++hd)
#pragma unroll
    for (int it = 0; it < 2; ++it)
      b[hd * 2 + it] = *reinterpret_cast<const bf16x8*>(
          &atn_s[(hd * 32 + it * 16 + mrow) * 36 + kg * 8]);

  f32x4 acc[16];
#pragma unroll
  for (int q = 0; q < 16; ++q) acc[q] = (f32x4){0.f, 0.f, 0.f, 0.f};
#pragma unroll
  for (int hd = 0; hd < 8; ++hd)
#pragma unroll
    for (int it = 0; it < 2; ++it)
      acc[hd * 2 + it] = __builtin_amdgcn_mfma_f32_16x16x32_bf16(
          a[hd], b[hd * 2 + it], acc[hd * 2 + it], 0, 0, 0);
  __syncthreads();

#pragma unroll
  for (int hd = 0; hd < 8; ++hd)
#pragma unroll
    for (int it = 0; it < 2; ++it) {
      f32x4 v = acc[hd * 2 + it];
      int col = hd * 32 + it * 16 + mrow;
#pragma unroll
      for (int r = 0; r < 4; ++r)
        vsm[(wave * 16 + kg * 4 + r) * 264 + col] = f2bf(v[r]);
    }
  unsigned short* tdst = tbuf + (size_t)bz * CC * HWC + R0 * 256;
#pragma unroll
  for (int k = 0; k < 8; ++k) {
    int n = k * 64 + lane;
    int rloc = n >> 5, c8 = n & 31;
    us8v v = *reinterpret_cast<const us8v*>(&vsm[(wave * 16 + rloc) * 264 + c8 * 8]);
    *reinterpret_cast<us8v*>(tdst + ((size_t)(wave * 16 + rloc)) * 256 + c8 * 8) = v;
  }
}

// K5b v2b: out = proj(t) + pb via MFMA. 64-px tiles x 8.
__global__ __launch_bounds__(256, 4) void k5b_proj(
    const unsigned short* __restrict__ tbuf, const float* __restrict__ pw,
    const float* __restrict__ pb, float* __restrict__ out, int b0)
{
  __shared__ __align__(16) unsigned short As2[2][64 * 106];
  const int t = threadIdx.x;
  const int bz = blockIdx.y;
  const unsigned short* tb = tbuf + (size_t)bz * CC * HWC;

  const int wave = t >> 6, lane = t & 63;
  const int wm = wave & 1, wn = wave >> 1;
  const int row = lane & 15, kg = lane >> 4;

  bf16x8 bfr[3][3];
  float bias[3];
#pragma unroll
  for (int nt = 0; nt < 3; ++nt) {
    int ocl = wn * 48 + nt * 16 + row;
    bias[nt] = pb[ocl];
#pragma unroll
    for (int kk = 0; kk < 3; ++kk) {
      const float* wp = pw + (size_t)ocl * 96 + kk * 32 + kg * 8;
      float4 w0 = *reinterpret_cast<const float4*>(wp);
      float4 w1 = *reinterpret_cast<const float4*>(wp + 4);
      us8v u;
      u[0] = f2bf(w0.x); u[1] = f2bf(w0.y); u[2] = f2bf(w0.z); u[3] = f2bf(w0.w);
      u[4] = f2bf(w1.x); u[5] = f2bf(w1.y); u[6] = f2bf(w1.z); u[7] = f2bf(w1.w);
      bfr[kk][nt] = *reinterpret_cast<bf16x8*>(&u);
    }
  }

  int sic[3], sp4[3];
#pragma unroll
  for (int r = 0; r < 3; ++r) {
    int lin = r * 256 + t;
    sic[r] = lin >> 4;
    sp4[r] = (lin & 15) * 4;
  }

  int p0 = blockIdx.x * 512;
  ushort4 ua0[3], ua1[3];
#pragma unroll
  for (int r = 0; r < 3; ++r) {
    ua0[r] = *reinterpret_cast<const ushort4*>(tb + (size_t)(2 * sic[r]) * HWC + p0 + sp4[r]);
    ua1[r] = *reinterpret_cast<const ushort4*>(tb + (size_t)(2 * sic[r] + 1) * HWC + p0 + sp4[r]);
  }

  for (int i = 0; i < 8; ++i) {
    unsigned short* Ac = As2[i & 1];
#pragma unroll
    for (int r = 0; r < 3; ++r) {
      unsigned short a0[4] = {ua0[r].x, ua0[r].y, ua0[r].z, ua0[r].w};
      unsigned short a1[4] = {ua1[r].x, ua1[r].y, ua1[r].z, ua1[r].w};
#pragma unroll
      for (int j = 0; j < 4; ++j) {
        unsigned pk = (unsigned)a0[j] | ((unsigned)a1[j] << 16);
        *reinterpret_cast<unsigned*>(&Ac[(sp4[r] + j) * 106 + 2 * sic[r]]) = pk;
      }
    }
    if (i < 7) {
      int p0n = p0 + 64;
#pragma unroll
      for (int r = 0; r < 3; ++r) {
        ua0[r] = *reinterpret_cast<const ushort4*>(tb + (size_t)(2 * sic[r]) * HWC + p0n + sp4[r]);
        ua1[r] = *reinterpret_cast<const ushort4*>(tb + (size_t)(2 * sic[r] + 1) * HWC + p0n + sp4[r]);
      }
    }
    __syncthreads();

    f32x4 acc[2][3];
#pragma unroll
    for (int mt = 0; mt < 2; ++mt)
#pragma unroll
      for (int nt = 0; nt < 3; ++nt) acc[mt][nt] = (f32x4){0.f, 0.f, 0.f, 0.f};
#pragma unroll
    for (int kk = 0; kk < 3; ++kk) {
      bf16x8 a[2];
#pragma unroll
      for (int mt = 0; mt < 2; ++mt)
        a[mt] = *reinterpret_cast<const bf16x8*>(
            &Ac[(wm * 32 + mt * 16 + row) * 106 + kk * 32 + kg * 8]);
#pragma unroll
      for (int mt = 0; mt < 2; ++mt)
#pragma unroll
        for (int nt = 0; nt < 3; ++nt)
          acc[mt][nt] = __builtin_amdgcn_mfma_f32_16x16x32_bf16(
              a[mt], bfr[kk][nt], acc[mt][nt], 0, 0, 0);
    }
    __syncthreads();

    float* tD = (float*)As2;   // [96][68] fp32, spans both buffers
#pragma unroll
    for (int nt = 0; nt < 3; ++nt) {
      int ocl = wn * 48 + nt * 16 + row;
      float bv = bias[nt];
#pragma unroll
      for (int mt = 0; mt < 2; ++mt) {
        int pxl = wm * 32 + mt * 16 + kg * 4;
        f32x4 v = acc[mt][nt];
        float4 w = make_float4(v[0] + bv, v[1] + bv, v[2] + bv, v[3] + bv);
        *reinterpret_cast<float4*>(&tD[ocl * 68 + pxl]) = w;
      }
    }
    __syncthreads();
    float* ob = out + (size_t)(b0 + bz) * CC * HWC + p0;
#pragma unroll
    for (int r = 0; r < 6; ++r) {
      int lin = r * 256 + t;
      int o = lin >> 4, p4 = (lin & 15) * 4;
      float4 v = *reinterpret_cast<const float4*>(&tD[o * 68 + p4]);
      *reinterpret_cast<float4*>(ob + (size_t)o * HWC + p4) = v;
    }
    __syncthreads();
    p0 += 64;
  }
}

extern "C" void kernel_launch(void* const* d_in, const int* in_sizes, int n_in,
                              void* d_out, int out_size, void* d_ws, size_t ws_size,
                              hipStream_t stream)
{
  const float* x      = (const float*)d_in[0];
  const float* qkv_w  = (const float*)d_in[1];
  const float* qkv_b  = (const float*)d_in[2];
  const float* dw_w   = (const float*)d_in[3];
  const float* dw_b   = (const float*)d_in[4];
  const float* proj_w = (const float*)d_in[5];
  const float* proj_b = (const float*)d_in[6];
  const float* temp   = (const float*)d_in[7];
  float* out = (float*)d_out;

  const size_t per_pre   = (size_t)C3 * HWC * 2;          // 37.75 MB
  const size_t per_dwo   = (size_t)192 * HWC * 2;         // 25.2 MB (q,k only)
  const size_t per_tbuf  = (size_t)CC * HWC * 2;          // 12.6 MB
  const size_t per_ssq   = (size_t)2 * 256 * 4;
  const size_t per_attn  = (size_t)NHEADS * 1024 * 4;
  const size_t per_gpart = (size_t)NHEADS * 24 * 1024 * 4;
  const size_t per_b = per_pre + per_dwo + per_tbuf + per_ssq + per_attn + per_gpart;

  int bc = 4;
  while (bc > 1 && per_b * (size_t)bc > ws_size) bc >>= 1;

  char* p = (char*)d_ws;
  unsigned short* pre  = (unsigned short*)p; p += per_pre * bc;
  unsigned short* dwo  = (unsigned short*)p; p += per_dwo * bc;
  unsigned short* tbuf = (unsigned short*)p; p += per_tbuf * bc;
  float* ssq   = (float*)p; p += per_ssq * bc;
  float* attn  = (float*)p; p += per_attn * bc;
  float* gpart = (float*)p; p += per_gpart * bc;

  for (int b0 = 0; b0 < 4; b0 += bc) {
    k1_qkv_mfma<<<dim3(128, 3, bc), 256, 0, stream>>>(x, qkv_w, qkv_b, pre, b0);
    k2_dw<<<dim3(192, 8, bc), 256, 0, stream>>>(pre, dw_w, dw_b, dwo);
    hipMemsetAsync(ssq, 0, per_ssq * bc, stream);
    k3_gram<<<dim3(24, NHEADS, bc), 256, 0, stream>>>(dwo, gpart, ssq);
    k4b_softmax<<<dim3(NHEADS, bc), 256, 0, stream>>>(gpart, ssq, temp, attn);
    k5a_attnv<<<dim3(384, bc), 256, 0, stream>>>(pre, dw_w, dw_b, attn, tbuf);
    k5b_proj<<<dim3(128, bc), 256, 0, stream>>>(tbuf, proj_w, proj_b, out, b0);
  }
}

// Round 16
// 222.615 us; speedup vs baseline: 1.0459x; 1.0025x over previous
//
#include <hip/hip_runtime.h>

#define CC 96
#define C3 288
#define HH 256
#define WW 256
#define HWC 65536
#define NHEADS 8
#define W2 32

typedef __bf16 bf16x8 __attribute__((ext_vector_type(8)));
typedef float f32x4 __attribute__((ext_vector_type(4)));
typedef unsigned short us8v __attribute__((ext_vector_type(8)));

__device__ __forceinline__ float bf2f(unsigned short u) {
  return __uint_as_float(((unsigned)u) << 16);
}
__device__ __forceinline__ unsigned short f2bf(float f) {
  unsigned u = __float_as_uint(f);
  unsigned r = u + 0x7fffu + ((u >> 16) & 1u);
  return (unsigned short)(r >> 16);
}

// K1 v4b: qkv conv1x1 via bf16 MFMA. 64-px tiles x 8, pipelined, 27KB LDS.
// grid (128, 3, bc): tile fastest -> same-x siblings share XCD L2.
__global__ __launch_bounds__(256, 4) void k1_qkv_mfma(
    const float* __restrict__ x, const float* __restrict__ qw,
    const float* __restrict__ qb, unsigned short* __restrict__ pre, int b0)
{
  __shared__ __align__(16) unsigned short As2[2][64 * 106];
  const int t = threadIdx.x;
  const int o0 = blockIdx.y * 96;
  const int bz = blockIdx.z;
  const float* xb = x + (size_t)(b0 + bz) * CC * HWC;

  const int wave = t >> 6, lane = t & 63;
  const int wm = wave & 1, wn = wave >> 1;
  const int row = lane & 15, kg = lane >> 4;

  bf16x8 bfr[3][3];
  float bias[3];
#pragma unroll
  for (int nt = 0; nt < 3; ++nt) {
    int ocl = wn * 48 + nt * 16 + row;
    bias[nt] = qb[o0 + ocl];
#pragma unroll
    for (int kk = 0; kk < 3; ++kk) {
      const float* wp = qw + (size_t)(o0 + ocl) * 96 + kk * 32 + kg * 8;
      float4 w0 = *reinterpret_cast<const float4*>(wp);
      float4 w1 = *reinterpret_cast<const float4*>(wp + 4);
      us8v u;
      u[0] = f2bf(w0.x); u[1] = f2bf(w0.y); u[2] = f2bf(w0.z); u[3] = f2bf(w0.w);
      u[4] = f2bf(w1.x); u[5] = f2bf(w1.y); u[6] = f2bf(w1.z); u[7] = f2bf(w1.w);
      bfr[kk][nt] = *reinterpret_cast<bf16x8*>(&u);
    }
  }

  int sic[3], sp4[3];
#pragma unroll
  for (int r = 0; r < 3; ++r) {
    int lin = r * 256 + t;
    sic[r] = lin >> 4;
    sp4[r] = (lin & 15) * 4;
  }

  int p0 = blockIdx.x * 512;
  float4 va0[3], va1[3];
#pragma unroll
  for (int r = 0; r < 3; ++r) {
    va0[r] = *reinterpret_cast<const float4*>(xb + (size_t)(2 * sic[r]) * HWC + p0 + sp4[r]);
    va1[r] = *reinterpret_cast<const float4*>(xb + (size_t)(2 * sic[r] + 1) * HWC + p0 + sp4[r]);
  }

  for (int i = 0; i < 8; ++i) {
    unsigned short* Ac = As2[i & 1];
#pragma unroll
    for (int r = 0; r < 3; ++r) {
      float a0[4] = {va0[r].x, va0[r].y, va0[r].z, va0[r].w};
      float a1[4] = {va1[r].x, va1[r].y, va1[r].z, va1[r].w};
#pragma unroll
      for (int j = 0; j < 4; ++j) {
        unsigned pk = (unsigned)f2bf(a0[j]) | ((unsigned)f2bf(a1[j]) << 16);
        *reinterpret_cast<unsigned*>(&Ac[(sp4[r] + j) * 106 + 2 * sic[r]]) = pk;
      }
    }
    if (i < 7) {
      int p0n = p0 + 64;
#pragma unroll
      for (int r = 0; r < 3; ++r) {
        va0[r] = *reinterpret_cast<const float4*>(xb + (size_t)(2 * sic[r]) * HWC + p0n + sp4[r]);
        va1[r] = *reinterpret_cast<const float4*>(xb + (size_t)(2 * sic[r] + 1) * HWC + p0n + sp4[r]);
      }
    }
    __syncthreads();

    f32x4 acc[2][3];
#pragma unroll
    for (int mt = 0; mt < 2; ++mt)
#pragma unroll
      for (int nt = 0; nt < 3; ++nt) acc[mt][nt] = (f32x4){0.f, 0.f, 0.f, 0.f};
#pragma unroll
    for (int kk = 0; kk < 3; ++kk) {
      bf16x8 a[2];
#pragma unroll
      for (int mt = 0; mt < 2; ++mt)
        a[mt] = *reinterpret_cast<const bf16x8*>(
            &Ac[(wm * 32 + mt * 16 + row) * 106 + kk * 32 + kg * 8]);
#pragma unroll
      for (int mt = 0; mt < 2; ++mt)
#pragma unroll
        for (int nt = 0; nt < 3; ++nt)
          acc[mt][nt] = __builtin_amdgcn_mfma_f32_16x16x32_bf16(
              a[mt], bfr[kk][nt], acc[mt][nt], 0, 0, 0);
    }
    __syncthreads();

    unsigned short* tD = (unsigned short*)As2;   // [96][72]
#pragma unroll
    for (int nt = 0; nt < 3; ++nt) {
      int ocl = wn * 48 + nt * 16 + row;
      float bv = bias[nt];
#pragma unroll
      for (int mt = 0; mt < 2; ++mt) {
        int pxl = wm * 32 + mt * 16 + kg * 4;
        f32x4 v = acc[mt][nt];
        unsigned pk0 = (unsigned)f2bf(v[0] + bv) | ((unsigned)f2bf(v[1] + bv) << 16);
        unsigned pk1 = (unsigned)f2bf(v[2] + bv) | ((unsigned)f2bf(v[3] + bv) << 16);
        *reinterpret_cast<unsigned*>(&tD[ocl * 72 + pxl]) = pk0;
        *reinterpret_cast<unsigned*>(&tD[ocl * 72 + pxl + 2]) = pk1;
      }
    }
    __syncthreads();
    unsigned short* preb = pre + ((size_t)bz * C3 + o0) * HWC + p0;
#pragma unroll
    for (int r = 0; r < 3; ++r) {
      int lin = r * 256 + t;
      int oc = lin >> 3, ch = lin & 7;
      us8v v = *reinterpret_cast<const us8v*>(&tD[oc * 72 + ch * 8]);
      *reinterpret_cast<us8v*>(preb + (size_t)oc * HWC + ch * 8) = v;
    }
    __syncthreads();
    p0 += 64;
  }
}

// K3 v5: dw(q,k) FUSED + Gram via bf16 MFMA. grid (24, 8, bc), block 256.
// Thread (hgroup 0..63, lw 0..3): 4 rows x 8 cols of this head's 32-col slice.
// dw in registers from pre (k2 pattern: shfl w-halo + scalar edge loads),
// packed straight into transposed qT/kT staging; sumsq from register outputs.
__global__ __launch_bounds__(256, 4) void k3_gram(
    const unsigned short* __restrict__ pre, const float* __restrict__ dww,
    const float* __restrict__ dwb, float* __restrict__ gpart,
    float* __restrict__ ssq)
{
  __shared__ __align__(16) unsigned short qT[32 * 264];
  __shared__ __align__(16) unsigned short kT[32 * 264];
  const int t = threadIdx.x;
  const int cg0 = blockIdx.x;
  const int head = blockIdx.y, bz = blockIdx.z;
  const int lane = t & 63, wave = t >> 6;
  const int mt = wave & 1, nt = wave >> 1;
  const int l15 = lane & 15, l4 = lane >> 4;
  const int hgroup = t >> 2;           // 0..63 -> rows hgroup*4..+4
  const int lw = t & 3;                // col group: 8 cols
  const int h0 = hgroup * 4;
  const int w0 = head * W2 + lw * 8;

  f32x4 acc = (f32x4){0.f, 0.f, 0.f, 0.f};
  float ssum_q = 0.f, ssum_k = 0.f;
  float o[4][8];

  for (int cc = 0; cc < 4; ++cc) {
    const int cq = cg0 * 4 + cc;
#pragma unroll
    for (int tensor = 0; tensor < 2; ++tensor) {
      const int ch = (tensor ? CC : 0) + cq;
      const unsigned short* src = pre + ((size_t)bz * C3 + ch) * HWC;
      const float* wg9 = dww + ch * 9;
      const float bias = dwb[ch];

      us8v rin[6];
#pragma unroll
      for (int r = 0; r < 6; ++r) {
        int hh = h0 - 1 + r;
        rin[r] = (hh >= 0 && hh < HH)
            ? *reinterpret_cast<const us8v*>(src + (size_t)hh * WW + w0)
            : (us8v){0, 0, 0, 0, 0, 0, 0, 0};
      }
      float eL[6], eR[6];
#pragma unroll
      for (int r = 0; r < 6; ++r) { eL[r] = 0.f; eR[r] = 0.f; }
      if (lw == 0 && head > 0) {
#pragma unroll
        for (int r = 0; r < 6; ++r) {
          int hh = h0 - 1 + r;
          if (hh >= 0 && hh < HH) eL[r] = bf2f(src[(size_t)hh * WW + w0 - 1]);
        }
      }
      if (lw == 3 && head < 7) {
#pragma unroll
        for (int r = 0; r < 6; ++r) {
          int hh = h0 - 1 + r;
          if (hh >= 0 && hh < HH) eR[r] = bf2f(src[(size_t)hh * WW + w0 + 8]);
        }
      }
      float f[6][8], lf[6], rt[6];
#pragma unroll
      for (int r = 0; r < 6; ++r) {
#pragma unroll
        for (int j = 0; j < 8; ++j) f[r][j] = bf2f(rin[r][j]);
        float l = __shfl_up(f[r][7], 1);
        float rr = __shfl_down(f[r][0], 1);
        lf[r] = (lw == 0) ? eL[r] : l;
        rt[r] = (lw == 3) ? eR[r] : rr;
      }
#pragma unroll
      for (int orow = 0; orow < 4; ++orow) {
#pragma unroll
        for (int j = 0; j < 8; ++j) o[orow][j] = bias;
#pragma unroll
        for (int k = 0; k < 3; ++k) {
          const int r = orow + k;
          const float w0_ = wg9[k * 3 + 0], w1_ = wg9[k * 3 + 1], w2_ = wg9[k * 3 + 2];
          o[orow][0] = fmaf(lf[r], w0_, fmaf(f[r][0], w1_, fmaf(f[r][1], w2_, o[orow][0])));
#pragma unroll
          for (int j = 1; j < 7; ++j)
            o[orow][j] = fmaf(f[r][j - 1], w0_, fmaf(f[r][j], w1_, fmaf(f[r][j + 1], w2_, o[orow][j])));
          o[orow][7] = fmaf(f[r][6], w0_, fmaf(f[r][7], w1_, fmaf(rt[r], w2_, o[orow][7])));
        }
      }
      if (tensor == 0) {
        __syncthreads();   // prev cc's MFMA reads of qT/kT complete
        unsigned* dst = reinterpret_cast<unsigned*>(qT);
#pragma unroll
        for (int j = 0; j < 8; ++j)
#pragma unroll
          for (int p = 0; p < 2; ++p)
            dst[(lw * 8 + j) * 132 + hgroup * 2 + p] =
                (unsigned)f2bf(o[2 * p][j]) | ((unsigned)f2bf(o[2 * p + 1][j]) << 16);
#pragma unroll
        for (int orow = 0; orow < 4; ++orow)
#pragma unroll
          for (int j = 0; j < 8; ++j) ssum_q = fmaf(o[orow][j], o[orow][j], ssum_q);
      } else {
        unsigned* dst = reinterpret_cast<unsigned*>(kT);
#pragma unroll
        for (int j = 0; j < 8; ++j)
#pragma unroll
          for (int p = 0; p < 2; ++p)
            dst[(lw * 8 + j) * 132 + hgroup * 2 + p] =
                (unsigned)f2bf(o[2 * p][j]) | ((unsigned)f2bf(o[2 * p + 1][j]) << 16);
#pragma unroll
        for (int orow = 0; orow < 4; ++orow)
#pragma unroll
          for (int j = 0; j < 8; ++j) ssum_k = fmaf(o[orow][j], o[orow][j], ssum_k);
      }
    }
    __syncthreads();   // qT/kT staged
#pragma unroll
    for (int kk = 0; kk < 8; ++kk) {
      bf16x8 a = *reinterpret_cast<const bf16x8*>(
          &qT[(mt * 16 + l15) * 264 + kk * 32 + l4 * 8]);
      bf16x8 b = *reinterpret_cast<const bf16x8*>(
          &kT[(nt * 16 + l15) * 264 + kk * 32 + l4 * 8]);
      acc = __builtin_amdgcn_mfma_f32_16x16x32_bf16(a, b, acc, 0, 0, 0);
    }
  }

  float* gp = gpart + (((size_t)bz * NHEADS + head) * 24 + cg0) * 1024;
#pragma unroll
  for (int reg = 0; reg < 4; ++reg)
    gp[(nt * 16 + l15) * 32 + mt * 16 + l4 * 4 + reg] = acc[reg];

  __syncthreads();   // all MFMA reads done; reuse qT as reduce scratch
  float* red = reinterpret_cast<float*>(qT);
  red[t] = ssum_q;
  red[256 + t] = ssum_k;
  __syncthreads();
  if (t < 32) {
    float sq = 0.f, sk = 0.f;
#pragma unroll
    for (int p = 0; p < 8; ++p) { sq += red[t + 32 * p]; sk += red[256 + t + 32 * p]; }
    atomicAdd(&ssq[(size_t)bz * 512 + head * W2 + t], sq);
    atomicAdd(&ssq[(size_t)bz * 512 + 256 + head * W2 + t], sk);
  }
}

// K4b v2: reduce gpart over 24 cg + normalize + temperature + softmax.
__global__ __launch_bounds__(256) void k4b_softmax(
    const float* __restrict__ gpart, const float* __restrict__ ssq,
    const float* __restrict__ temp, float* __restrict__ attn)
{
  __shared__ float lg[1024];
  const int t = threadIdx.x;
  const int head = blockIdx.x, bz = blockIdx.y;
  const float* gp = gpart + ((size_t)bz * NHEADS + head) * 24 * 1024;
  float4 s = make_float4(0.f, 0.f, 0.f, 0.f);
#pragma unroll 4
  for (int cg = 0; cg < 24; ++cg) {
    float4 v = *reinterpret_cast<const float4*>(gp + cg * 1024 + t * 4);
    s.x += v.x; s.y += v.y; s.z += v.z; s.w += v.w;
  }
  *reinterpret_cast<float4*>(&lg[t * 4]) = s;
  __syncthreads();
  if (t < 32) {
    const int i = t;
    const float* sq_ = ssq + (size_t)bz * 512 + head * W2;
    const float* sk_ = ssq + (size_t)bz * 512 + 256 + head * W2;
    float invq = 1.f / fmaxf(sqrtf(sq_[i]), 1e-12f);
    float tpq = temp[head] * invq;
    float rowv[32];
    float m = -1e30f;
#pragma unroll
    for (int j = 0; j < 32; ++j) {
      float invk = 1.f / fmaxf(sqrtf(sk_[j]), 1e-12f);
      float v = lg[j * 32 + i] * tpq * invk;
      rowv[j] = v;
      m = fmaxf(m, v);
    }
    float ssum = 0;
#pragma unroll
    for (int j = 0; j < 32; ++j) { rowv[j] = expf(rowv[j] - m); ssum += rowv[j]; }
    float inv = 1.f / ssum;
    float* ap = attn + ((size_t)bz * NHEADS + head) * 1024 + i * 32;
#pragma unroll
    for (int j = 0; j < 32; ++j) ap[j] = rowv[j] * inv;
  }
}

// K5a v2: dw(v) FUSED + attn @ v via MFMA. grid (384, bc), block 256.
__global__ __launch_bounds__(256) void k5a_attnv(
    const unsigned short* __restrict__ pre, const float* __restrict__ dww,
    const float* __restrict__ dwb, const float* __restrict__ attn,
    unsigned short* __restrict__ tbuf)
{
  __shared__ __align__(16) unsigned short vsm[64 * 264];
  __shared__ __align__(16) unsigned short atn_s[256 * 36];
  const int t = threadIdx.x;
  const int tile = blockIdx.x;
  const int bz = blockIdx.y;
  const size_t R0 = (size_t)tile * 64;
  const int c = tile >> 2;
  const int h0 = (tile & 3) * 64;
  const unsigned short* vsrc = pre + ((size_t)bz * C3 + 2 * CC + c) * HWC;
  const int team = t >> 5, tl = t & 31;

  float4 av[8];
  {
    const float* ap = attn + (size_t)bz * 8192 + t * 32;
#pragma unroll
    for (int k = 0; k < 8; ++k)
      av[k] = *reinterpret_cast<const float4*>(ap + k * 4);
  }

  float wg[9];
#pragma unroll
  for (int i = 0; i < 9; ++i) wg[i] = dww[(2 * CC + c) * 9 + i];
  const float vbias = dwb[2 * CC + c];

#pragma unroll
  for (int p = 0; p < 2; ++p) {
    const int hb = h0 + team * 8 + p * 4;
    us8v rin[6];
#pragma unroll
    for (int r = 0; r < 6; ++r) {
      int hh = hb - 1 + r;
      if (hh >= 0 && hh < HH)
        rin[r] = *reinterpret_cast<const us8v*>(vsrc + (size_t)hh * WW + tl * 8);
      else
        rin[r] = (us8v){0, 0, 0, 0, 0, 0, 0, 0};
    }
    float f[6][8], lf[6], rt[6];
#pragma unroll
    for (int r = 0; r < 6; ++r) {
#pragma unroll
      for (int j = 0; j < 8; ++j) f[r][j] = bf2f(rin[r][j]);
      float l = __shfl_up(f[r][7], 1, 32);
      float rr = __shfl_down(f[r][0], 1, 32);
      lf[r] = (tl == 0) ? 0.f : l;
      rt[r] = (tl == 31) ? 0.f : rr;
    }
#pragma unroll
    for (int orow = 0; orow < 4; ++orow) {
      float o[8];
#pragma unroll
      for (int j = 0; j < 8; ++j) o[j] = vbias;
#pragma unroll
      for (int k = 0; k < 3; ++k) {
        const int r = orow + k;
        const float w0 = wg[k * 3 + 0], w1 = wg[k * 3 + 1], w2 = wg[k * 3 + 2];
        o[0] = fmaf(lf[r], w0, fmaf(f[r][0], w1, fmaf(f[r][1], w2, o[0])));
#pragma unroll
        for (int j = 1; j < 7; ++j)
          o[j] = fmaf(f[r][j - 1], w0, fmaf(f[r][j], w1, fmaf(f[r][j + 1], w2, o[j])));
        o[7] = fmaf(f[r][6], w0, fmaf(f[r][7], w1, fmaf(rt[r], w2, o[7])));
      }
      us8v u;
#pragma unroll
      for (int j = 0; j < 8; ++j) u[j] = f2bf(o[j]);
      int rl = team * 8 + p * 4 + orow;
      *reinterpret_cast<us8v*>(&vsm[rl * 264 + tl * 8]) = u;
    }
  }
#pragma unroll
  for (int k = 0; k < 8; ++k) {
    ushort4 u;
    u.x = f2bf(av[k].x); u.y = f2bf(av[k].y); u.z = f2bf(av[k].z); u.w = f2bf(av[k].w);
    *reinterpret_cast<ushort4*>(&atn_s[t * 36 + k * 4]) = u;
  }
  __syncthreads();

  const int wave = t >> 6, lane = t & 63;
  const int mrow = lane & 15, kg = lane >> 4;

  bf16x8 a[8], b[16];
#pragma unroll
  for (int hd = 0; hd < 8; ++hd)
    a[hd] = *reinterpret_cast<const bf16x8*>(
        &vsm[(wave * 16 + mrow) * 264 + hd * 32 + kg * 8]);
#pragma unroll
  for (int hd = 0; hd < 8; ++hd)
#pragma unroll
    for (int it = 0; it < 2; ++it)
      b[hd * 2 + it] = *reinterpret_cast<const bf16x8*>(
          &atn_s[(hd * 32 + it * 16 + mrow) * 36 + kg * 8]);

  f32x4 acc[16];
#pragma unroll
  for (int q = 0; q < 16; ++q) acc[q] = (f32x4){0.f, 0.f, 0.f, 0.f};
#pragma unroll
  for (int hd = 0; hd < 8; ++hd)
#pragma unroll
    for (int it = 0; it < 2; ++it)
      acc[hd * 2 + it] = __builtin_amdgcn_mfma_f32_16x16x32_bf16(
          a[hd], b[hd * 2 + it], acc[hd * 2 + it], 0, 0, 0);
  __syncthreads();

#pragma unroll
  for (int hd = 0; hd < 8; ++hd)
#pragma unroll
    for (int it = 0; it < 2; ++it) {
      f32x4 v = acc[hd * 2 + it];
      int col = hd * 32 + it * 16 + mrow;
#pragma unroll
      for (int r = 0; r < 4; ++r)
        vsm[(wave * 16 + kg * 4 + r) * 264 + col] = f2bf(v[r]);
    }
  unsigned short* tdst = tbuf + (size_t)bz * CC * HWC + R0 * 256;
#pragma unroll
  for (int k = 0; k < 8; ++k) {
    int n = k * 64 + lane;
    int rloc = n >> 5, c8 = n & 31;
    us8v v = *reinterpret_cast<const us8v*>(&vsm[(wave * 16 + rloc) * 264 + c8 * 8]);
    *reinterpret_cast<us8v*>(tdst + ((size_t)(wave * 16 + rloc)) * 256 + c8 * 8) = v;
  }
}

// K5b v2b: out = proj(t) + pb via MFMA. 64-px tiles x 8.
__global__ __launch_bounds__(256, 4) void k5b_proj(
    const unsigned short* __restrict__ tbuf, const float* __restrict__ pw,
    const float* __restrict__ pb, float* __restrict__ out, int b0)
{
  __shared__ __align__(16) unsigned short As2[2][64 * 106];
  const int t = threadIdx.x;
  const int bz = blockIdx.y;
  const unsigned short* tb = tbuf + (size_t)bz * CC * HWC;

  const int wave = t >> 6, lane = t & 63;
  const int wm = wave & 1, wn = wave >> 1;
  const int row = lane & 15, kg = lane >> 4;

  bf16x8 bfr[3][3];
  float bias[3];
#pragma unroll
  for (int nt = 0; nt < 3; ++nt) {
    int ocl = wn * 48 + nt * 16 + row;
    bias[nt] = pb[ocl];
#pragma unroll
    for (int kk = 0; kk < 3; ++kk) {
      const float* wp = pw + (size_t)ocl * 96 + kk * 32 + kg * 8;
      float4 w0 = *reinterpret_cast<const float4*>(wp);
      float4 w1 = *reinterpret_cast<const float4*>(wp + 4);
      us8v u;
      u[0] = f2bf(w0.x); u[1] = f2bf(w0.y); u[2] = f2bf(w0.z); u[3] = f2bf(w0.w);
      u[4] = f2bf(w1.x); u[5] = f2bf(w1.y); u[6] = f2bf(w1.z); u[7] = f2bf(w1.w);
      bfr[kk][nt] = *reinterpret_cast<bf16x8*>(&u);
    }
  }

  int sic[3], sp4[3];
#pragma unroll
  for (int r = 0; r < 3; ++r) {
    int lin = r * 256 + t;
    sic[r] = lin >> 4;
    sp4[r] = (lin & 15) * 4;
  }

  int p0 = blockIdx.x * 512;
  ushort4 ua0[3], ua1[3];
#pragma unroll
  for (int r = 0; r < 3; ++r) {
    ua0[r] = *reinterpret_cast<const ushort4*>(tb + (size_t)(2 * sic[r]) * HWC + p0 + sp4[r]);
    ua1[r] = *reinterpret_cast<const ushort4*>(tb + (size_t)(2 * sic[r] + 1) * HWC + p0 + sp4[r]);
  }

  for (int i = 0; i < 8; ++i) {
    unsigned short* Ac = As2[i & 1];
#pragma unroll
    for (int r = 0; r < 3; ++r) {
      unsigned short a0[4] = {ua0[r].x, ua0[r].y, ua0[r].z, ua0[r].w};
      unsigned short a1[4] = {ua1[r].x, ua1[r].y, ua1[r].z, ua1[r].w};
#pragma unroll
      for (int j = 0; j < 4; ++j) {
        unsigned pk = (unsigned)a0[j] | ((unsigned)a1[j] << 16);
        *reinterpret_cast<unsigned*>(&Ac[(sp4[r] + j) * 106 + 2 * sic[r]]) = pk;
      }
    }
    if (i < 7) {
      int p0n = p0 + 64;
#pragma unroll
      for (int r = 0; r < 3; ++r) {
        ua0[r] = *reinterpret_cast<const ushort4*>(tb + (size_t)(2 * sic[r]) * HWC + p0n + sp4[r]);
        ua1[r] = *reinterpret_cast<const ushort4*>(tb + (size_t)(2 * sic[r] + 1) * HWC + p0n + sp4[r]);
      }
    }
    __syncthreads();

    f32x4 acc[2][3];
#pragma unroll
    for (int mt = 0; mt < 2; ++mt)
#pragma unroll
      for (int nt = 0; nt < 3; ++nt) acc[mt][nt] = (f32x4){0.f, 0.f, 0.f, 0.f};
#pragma unroll
    for (int kk = 0; kk < 3; ++kk) {
      bf16x8 a[2];
#pragma unroll
      for (int mt = 0; mt < 2; ++mt)
        a[mt] = *reinterpret_cast<const bf16x8*>(
            &Ac[(wm * 32 + mt * 16 + row) * 106 + kk * 32 + kg * 8]);
#pragma unroll
      for (int mt = 0; mt < 2; ++mt)
#pragma unroll
        for (int nt = 0; nt < 3; ++nt)
          acc[mt][nt] = __builtin_amdgcn_mfma_f32_16x16x32_bf16(
              a[mt], bfr[kk][nt], acc[mt][nt], 0, 0, 0);
    }
    __syncthreads();

    float* tD = (float*)As2;   // [96][68] fp32, spans both buffers
#pragma unroll
    for (int nt = 0; nt < 3; ++nt) {
      int ocl = wn * 48 + nt * 16 + row;
      float bv = bias[nt];
#pragma unroll
      for (int mt = 0; mt < 2; ++mt) {
        int pxl = wm * 32 + mt * 16 + kg * 4;
        f32x4 v = acc[mt][nt];
        float4 w = make_float4(v[0] + bv, v[1] + bv, v[2] + bv, v[3] + bv);
        *reinterpret_cast<float4*>(&tD[ocl * 68 + pxl]) = w;
      }
    }
    __syncthreads();
    float* ob = out + (size_t)(b0 + bz) * CC * HWC + p0;
#pragma unroll
    for (int r = 0; r < 6; ++r) {
      int lin = r * 256 + t;
      int o = lin >> 4, p4 = (lin & 15) * 4;
      float4 v = *reinterpret_cast<const float4*>(&tD[o * 68 + p4]);
      *reinterpret_cast<float4*>(ob + (size_t)o * HWC + p4) = v;
    }
    __syncthreads();
    p0 += 64;
  }
}

extern "C" void kernel_launch(void* const* d_in, const int* in_sizes, int n_in,
                              void* d_out, int out_size, void* d_ws, size_t ws_size,
                              hipStream_t stream)
{
  const float* x      = (const float*)d_in[0];
  const float* qkv_w  = (const float*)d_in[1];
  const float* qkv_b  = (const float*)d_in[2];
  const float* dw_w   = (const float*)d_in[3];
  const float* dw_b   = (const float*)d_in[4];
  const float* proj_w = (const float*)d_in[5];
  const float* proj_b = (const float*)d_in[6];
  const float* temp   = (const float*)d_in[7];
  float* out = (float*)d_out;

  const size_t per_pre   = (size_t)C3 * HWC * 2;          // 37.75 MB
  const size_t per_tbuf  = (size_t)CC * HWC * 2;          // 12.6 MB
  const size_t per_ssq   = (size_t)2 * 256 * 4;
  const size_t per_attn  = (size_t)NHEADS * 1024 * 4;
  const size_t per_gpart = (size_t)NHEADS * 24 * 1024 * 4;
  const size_t per_b = per_pre + per_tbuf + per_ssq + per_attn + per_gpart;

  int bc = 4;
  while (bc > 1 && per_b * (size_t)bc > ws_size) bc >>= 1;

  char* p = (char*)d_ws;
  unsigned short* pre  = (unsigned short*)p; p += per_pre * bc;
  unsigned short* tbuf = (unsigned short*)p; p += per_tbuf * bc;
  float* ssq   = (float*)p; p += per_ssq * bc;
  float* attn  = (float*)p; p += per_attn * bc;
  float* gpart = (float*)p; p += per_gpart * bc;

  for (int b0 = 0; b0 < 4; b0 += bc) {
    k1_qkv_mfma<<<dim3(128, 3, bc), 256, 0, stream>>>(x, qkv_w, qkv_b, pre, b0);
    hipMemsetAsync(ssq, 0, per_ssq * bc, stream);
    k3_gram<<<dim3(24, NHEADS, bc), 256, 0, stream>>>(pre, dw_w, dw_b, gpart, ssq);
    k4b_softmax<<<dim3(NHEADS, bc), 256, 0, stream>>>(gpart, ssq, temp, attn);
    k5a_attnv<<<dim3(384, bc), 256, 0, stream>>>(pre, dw_w, dw_b, attn, tbuf);
    k5b_proj<<<dim3(128, bc), 256, 0, stream>>>(tbuf, proj_w, proj_b, out, b0);
  }
}